// Round 2
// baseline (12394.250 us; speedup 1.0000x reference)
//
#include <hip/hip_runtime.h>
#include <hip/hip_bf16.h>
#include <math.h>

// ---------------- problem constants ----------------
#define B_   128
#define S_   50
#define BS_  (B_*S_)        // 6400
#define E_   512
#define D_   1024
#define H_   16
#define DK_  64
#define L_   4
#define FF_  4096
#define V_   100000

__device__ __forceinline__ float gelu_exact(float x) {
    return 0.5f * x * (1.0f + erff(x * 0.70710678118654752440f));
}

// ---------------- embedding gather + concat ----------------
// xin[bs][1536] = [movie_table[mid], fran_table[fid], entry_table[eid]]
__global__ __launch_bounds__(256) void embed_concat(
    const float* __restrict__ mt, const float* __restrict__ ft, const float* __restrict__ et,
    const int* __restrict__ mids, const int* __restrict__ fids, const int* __restrict__ eids,
    float* __restrict__ xin)
{
    int bs = blockIdx.x;
    int mid = mids[bs], fid = fids[bs], eid = eids[bs];
    const float* srcs[3] = { mt + (size_t)mid * E_, ft + (size_t)fid * E_, et + (size_t)eid * E_ };
    float* dst = xin + (size_t)bs * (3 * E_);
    for (int i = threadIdx.x; i < 384; i += 256) {       // 384 float4 = 1536 floats
        int seg = i >> 7, off = i & 127;                  // 128 float4 per 512-seg
        reinterpret_cast<float4*>(dst + seg * E_)[off] =
            reinterpret_cast<const float4*>(srcs[seg])[off];
    }
}

// ---------------- positional encoding add ----------------
__global__ __launch_bounds__(256) void pe_add(float* __restrict__ x)
{
    int row = blockIdx.x;           // b*S + s
    int s = row % S_;
    float* px = x + (size_t)row * D_;
    const float c = -logf(10000.0f) / 512.0f;
    for (int d = threadIdx.x; d < D_; d += 256) {
        int second = d >= 512;
        int cc = second ? d - 512 : d;
        int i = cc >> 1;
        float div = expf(c * (float)(2 * i));
        float a = (float)s * div * (second ? 1.5f : 1.0f);
        float pe = (cc & 1) ? cosf(a) : sinf(a);
        px[d] += pe;
    }
}

// ---------------- generic tiled fp32 GEMM: C = A[M,K] @ W[K,N] + bias, act ----------------
// act: 0 none, 1 gelu(exact), 2 sigmoid
// requires: M % 64 == 0, K % 16 == 0 (true for all calls); N arbitrary.
__global__ __launch_bounds__(256) void gemm_bias_act(
    const float* __restrict__ A, const float* __restrict__ W,
    const float* __restrict__ bias, float* __restrict__ C,
    int M, int N, int K, int act)
{
    __shared__ float As[16][64];
    __shared__ float Bs[16][68];
    const int tid = threadIdx.x;
    const int rowBase = blockIdx.y * 64;
    const int colBase = blockIdx.x * 64;
    const int tx = tid & 15, ty = tid >> 4;
    const int arow = tid >> 2;
    const int ak4  = (tid & 3) << 2;
    const int brow = tid >> 4;
    const int bn4  = (tid & 15) << 2;
    const bool fullN = (colBase + 64 <= N);

    float acc[4][4] = {};

    for (int kb = 0; kb < K; kb += 16) {
        float4 av = *reinterpret_cast<const float4*>(&A[(size_t)(rowBase + arow) * K + kb + ak4]);
        As[ak4 + 0][arow] = av.x;
        As[ak4 + 1][arow] = av.y;
        As[ak4 + 2][arow] = av.z;
        As[ak4 + 3][arow] = av.w;
        if (fullN) {
            float4 bv = *reinterpret_cast<const float4*>(&W[(size_t)(kb + brow) * N + colBase + bn4]);
            *reinterpret_cast<float4*>(&Bs[brow][bn4]) = bv;
        } else {
            #pragma unroll
            for (int t = 0; t < 4; ++t) {
                int n = colBase + bn4 + t;
                Bs[brow][bn4 + t] = (n < N) ? W[(size_t)(kb + brow) * N + n] : 0.0f;
            }
        }
        __syncthreads();
        #pragma unroll
        for (int kk = 0; kk < 16; ++kk) {
            float4 a4 = *reinterpret_cast<const float4*>(&As[kk][ty << 2]);
            float4 b4 = *reinterpret_cast<const float4*>(&Bs[kk][tx << 2]);
            float ar[4] = { a4.x, a4.y, a4.z, a4.w };
            float br[4] = { b4.x, b4.y, b4.z, b4.w };
            #pragma unroll
            for (int i = 0; i < 4; ++i)
                #pragma unroll
                for (int j = 0; j < 4; ++j)
                    acc[i][j] += ar[i] * br[j];
        }
        __syncthreads();
    }

    #pragma unroll
    for (int i = 0; i < 4; ++i) {
        int r = rowBase + (ty << 2) + i;
        #pragma unroll
        for (int j = 0; j < 4; ++j) {
            int c = colBase + (tx << 2) + j;
            if (c < N) {
                float v = acc[i][j] + (bias ? bias[c] : 0.0f);
                if (act == 1) v = gelu_exact(v);
                else if (act == 2) v = 1.0f / (1.0f + expf(-v));
                C[(size_t)r * N + c] = v;
            }
        }
    }
}

// ---------------- rel gather: rel[i][j][d] = rel_table_l[rm[i*S+j]][d] ----------------
__global__ __launch_bounds__(256) void rel_gather(
    const float* __restrict__ rt, const int* __restrict__ rm, float* __restrict__ rel)
{
    int idx = blockIdx.x * 256 + threadIdx.x;
    if (idx >= S_ * S_ * DK_) return;
    int d = idx & 63;
    int ij = idx >> 6;
    rel[idx] = rt[(size_t)rm[ij] * DK_ + d];
}

// ---------------- self-attention (per (b,h) block) ----------------
// q,k,v: [BS, D] with head h at cols h*64..; rel: [S,S,64]; ctx out: [BS, D]
__global__ __launch_bounds__(256) void attn_kernel(
    const float* __restrict__ q, const float* __restrict__ k, const float* __restrict__ v,
    const float* __restrict__ rel, float* __restrict__ ctx)
{
    int bh = blockIdx.x;
    int b = bh >> 4, h = bh & 15;
    __shared__ float qs[S_][DK_], ks[S_][DK_], vs[S_][DK_];
    int tid = threadIdx.x;
    int wave = tid >> 6, lane = tid & 63;

    for (int idx = tid; idx < S_ * DK_; idx += 256) {
        int s = idx >> 6, d = idx & 63;
        size_t g = ((size_t)(b * S_ + s)) * D_ + h * DK_ + d;
        qs[s][d] = q[g];
        ks[s][d] = k[g];
        vs[s][d] = v[g];
    }
    __syncthreads();

    const float scale = 0.125f; // 1/sqrt(64)
    for (int i = wave; i < S_; i += 4) {
        float sc = -INFINITY;
        if (lane < S_) {
            float acc = 0.0f, accr = 0.0f;
            const float* rrow = rel + ((size_t)i * S_ + lane) * DK_;
            #pragma unroll 8
            for (int d = 0; d < DK_; ++d) {
                float qd = qs[i][d];
                acc  += qd * ks[lane][d];
                accr += qd * rrow[d];
            }
            sc = acc * scale + 0.5f * accr;
        }
        float m = sc;
        #pragma unroll
        for (int off = 32; off; off >>= 1) m = fmaxf(m, __shfl_xor(m, off));
        float e = (lane < S_) ? expf(sc - m) : 0.0f;
        float sum = e;
        #pragma unroll
        for (int off = 32; off; off >>= 1) sum += __shfl_xor(sum, off);
        float aval = e / sum;    // lane j holds attn[i][j]; lanes >= 50 hold 0

        float acc = 0.0f;
        for (int j = 0; j < S_; ++j) {
            float aj = __shfl(aval, j);
            acc += aj * vs[j][lane];
        }
        ctx[((size_t)(b * S_ + i)) * D_ + h * DK_ + lane] = acc;
    }
}

// ---------------- add + layernorm: out = LN(a + res) * g + be ----------------
__global__ __launch_bounds__(256) void add_ln(
    const float* __restrict__ a, const float* __restrict__ res,
    const float* __restrict__ g, const float* __restrict__ be,
    float* __restrict__ out)
{
    int row = blockIdx.x, tid = threadIdx.x;
    const float* pa = a + (size_t)row * D_;
    const float* pr = res + (size_t)row * D_;
    float vals[4];
    float s = 0.0f;
    #pragma unroll
    for (int t = 0; t < 4; ++t) {
        float v = pa[tid + t * 256] + pr[tid + t * 256];
        vals[t] = v;
        s += v;
    }
    __shared__ float red[8];
    #pragma unroll
    for (int off = 32; off; off >>= 1) s += __shfl_xor(s, off);
    int wave = tid >> 6, lane = tid & 63;
    if (lane == 0) red[wave] = s;
    __syncthreads();
    float mean = (red[0] + red[1] + red[2] + red[3]) * (1.0f / D_);
    float vs = 0.0f;
    #pragma unroll
    for (int t = 0; t < 4; ++t) {
        float d = vals[t] - mean;
        vs += d * d;
    }
    #pragma unroll
    for (int off = 32; off; off >>= 1) vs += __shfl_xor(vs, off);
    if (lane == 0) red[4 + wave] = vs;
    __syncthreads();
    float var = (red[4] + red[5] + red[6] + red[7]) * (1.0f / D_);
    float rstd = rsqrtf(var + 1e-5f);
    float* po = out + (size_t)row * D_;
    #pragma unroll
    for (int t = 0; t < 4; ++t) {
        int c = tid + t * 256;
        po[c] = (vals[t] - mean) * rstd * g[c] + be[c];
    }
}

// ---------------- user embedding gather ----------------
__global__ __launch_bounds__(256) void gather_user(
    const float* __restrict__ ut, const int* __restrict__ ids, float* __restrict__ out)
{
    int b = blockIdx.x;
    int uid = ids[b];
    for (int d = threadIdx.x; d < D_; d += 256)
        out[(size_t)b * D_ + d] = ut[(size_t)uid * D_ + d];
}

// ---------------- cross attention (q_len = 1) ----------------
__global__ __launch_bounds__(64) void cross_attn(
    const float* __restrict__ qh, const float* __restrict__ kh, const float* __restrict__ vh,
    float* __restrict__ up)
{
    int bh = blockIdx.x;
    int b = bh >> 4, h = bh & 15;
    int lane = threadIdx.x;
    __shared__ float qv[DK_];
    qv[lane] = qh[(size_t)b * D_ + h * DK_ + lane];
    __syncthreads();
    float sc = -INFINITY;
    if (lane < S_) {
        float acc = 0.0f;
        const float* krow = kh + ((size_t)(b * S_ + lane)) * D_ + h * DK_;
        #pragma unroll 8
        for (int d = 0; d < DK_; ++d) acc += qv[d] * krow[d];
        sc = acc * 0.125f;
    }
    float m = sc;
    #pragma unroll
    for (int off = 32; off; off >>= 1) m = fmaxf(m, __shfl_xor(m, off));
    float e = (lane < S_) ? expf(sc - m) : 0.0f;
    float sum = e;
    #pragma unroll
    for (int off = 32; off; off >>= 1) sum += __shfl_xor(sum, off);
    float aval = e / sum;
    float acc = 0.0f;
    for (int j = 0; j < S_; ++j) {
        float aj = __shfl(aval, j);
        acc += aj * vh[((size_t)(b * S_ + j)) * D_ + h * DK_ + lane];
    }
    up[(size_t)b * D_ + h * DK_ + lane] = acc;
}

// ---------------- sequence mean over s ----------------
__global__ __launch_bounds__(256) void seq_mean(const float* __restrict__ x, float* __restrict__ out)
{
    int b = blockIdx.x;
    for (int d = threadIdx.x; d < D_; d += 256) {
        float s = 0.0f;
        for (int si = 0; si < S_; ++si)
            s += x[((size_t)(b * S_ + si)) * D_ + d];
        out[(size_t)b * D_ + d] = s * (1.0f / S_);
    }
}

// ---------------- column copy (for concat) ----------------
__global__ __launch_bounds__(256) void copy_cols(
    const float* __restrict__ src, float* __restrict__ dst,
    int width, int dstStride, int dstOff)
{
    int r = blockIdx.x;
    for (int c = threadIdx.x; c < width; c += 256)
        dst[(size_t)r * dstStride + dstOff + c] = src[(size_t)r * width + c];
}

// ---------------- order softmax ([128,2]) ----------------
__global__ __launch_bounds__(128) void order_softmax(const float* __restrict__ in, float* __restrict__ out)
{
    int b = threadIdx.x;
    if (b >= B_) return;
    float a = in[b * 2], c = in[b * 2 + 1];
    float m = fmaxf(a, c);
    float ea = expf(a - m), ec = expf(c - m);
    float s = ea + ec;
    out[b * 2] = ea / s;
    out[b * 2 + 1] = ec / s;
}

// ---------------- host-side launcher ----------------
extern "C" void kernel_launch(void* const* d_in, const int* in_sizes, int n_in,
                              void* d_out, int out_size, void* d_ws, size_t ws_size,
                              hipStream_t stream) {
    const float* movie_table = (const float*)d_in[0];
    const float* fran_table  = (const float*)d_in[1];
    const float* entry_table = (const float*)d_in[2];
    const float* proj_w      = (const float*)d_in[3];
    const float* proj_b      = (const float*)d_in[4];
    const float* wq          = (const float*)d_in[5];
    const float* bq          = (const float*)d_in[6];
    const float* wk          = (const float*)d_in[7];
    const float* bk          = (const float*)d_in[8];
    const float* wv          = (const float*)d_in[9];
    const float* bv          = (const float*)d_in[10];
    const float* wo          = (const float*)d_in[11];
    const float* bo          = (const float*)d_in[12];
    const float* rel_table   = (const float*)d_in[13];
    const float* aln_g       = (const float*)d_in[14];
    const float* aln_b       = (const float*)d_in[15];
    const float* f_w1        = (const float*)d_in[16];
    const float* f_b1        = (const float*)d_in[17];
    const float* f_w2        = (const float*)d_in[18];
    const float* f_b2        = (const float*)d_in[19];
    const float* ln_g        = (const float*)d_in[20];
    const float* ln_b        = (const float*)d_in[21];
    const float* user_table  = (const float*)d_in[22];
    const float* mq_w        = (const float*)d_in[23];
    const float* mq_b        = (const float*)d_in[24];
    const float* mk_w        = (const float*)d_in[25];
    const float* mk_b        = (const float*)d_in[26];
    const float* mv_w        = (const float*)d_in[27];
    const float* mv_b        = (const float*)d_in[28];
    const float* mo_w        = (const float*)d_in[29];
    const float* mo_b        = (const float*)d_in[30];
    const float* c_w1        = (const float*)d_in[31];
    const float* c_b1        = (const float*)d_in[32];
    const float* c_w2        = (const float*)d_in[33];
    const float* c_b2        = (const float*)d_in[34];
    const float* n_w1        = (const float*)d_in[35];
    const float* n_b1        = (const float*)d_in[36];
    const float* n_w2        = (const float*)d_in[37];
    const float* n_b2        = (const float*)d_in[38];
    const float* r_w1        = (const float*)d_in[39];
    const float* r_b1        = (const float*)d_in[40];
    const float* r_w2        = (const float*)d_in[41];
    const float* r_b2        = (const float*)d_in[42];
    const float* o_w1        = (const float*)d_in[43];
    const float* o_b1        = (const float*)d_in[44];
    const float* o_w2        = (const float*)d_in[45];
    const float* o_b2        = (const float*)d_in[46];
    const int* user_ids      = (const int*)d_in[47];
    const int* movie_ids     = (const int*)d_in[48];
    const int* franchise_ids = (const int*)d_in[49];
    const int* entry_types   = (const int*)d_in[50];
    const int* relation_mat  = (const int*)d_in[51];

    // ---- workspace layout (floats) ----
    float* ws = (float*)d_ws;
    float* xin      = ws;                        // BS*1536 = 9,830,400 (also reused for attn_out/ff2)
    float* q        = xin + (size_t)BS_ * 1536;  // BS*D
    float* k        = q   + (size_t)BS_ * D_;
    float* v        = k   + (size_t)BS_ * D_;
    float* ctx      = v   + (size_t)BS_ * D_;
    float* ff       = ctx + (size_t)BS_ * D_;    // BS*FF
    float* rel      = ff  + (size_t)BS_ * FF_;   // S*S*DK
    float* user_emb = rel + (size_t)S_ * S_ * DK_;
    float* up_pre   = user_emb + (size_t)B_ * D_;
    float* seq      = up_pre   + (size_t)B_ * D_;
    float* ci       = seq      + (size_t)B_ * D_;   // B * 2D
    float* ri       = ci       + (size_t)B_ * 2 * D_; // B * 3D
    float* h1       = ri       + (size_t)B_ * 3 * D_; // B * D
    float* ho       = h1       + (size_t)B_ * D_;     // B * 512

    // ---- d_out layout ----
    float* xout    = (float*)d_out;                 // [BS, D]
    float* comp    = xout + (size_t)BS_ * D_;       // [B,1]
    float* logits  = comp + B_;                     // [B,V]
    float* rating  = logits + (size_t)B_ * V_;      // [B,1]
    float* order   = rating + B_;                   // [B,2]
    float* upref   = order + 2 * B_;                // [B,D]

    dim3 blk(256);
    dim3 gemm_big((D_ + 63) / 64, BS_ / 64);        // N=1024, M=6400

    // 1) embeddings + projection + PE
    embed_concat<<<BS_, blk, 0, stream>>>(movie_table, fran_table, entry_table,
                                          movie_ids, franchise_ids, entry_types, xin);
    gemm_bias_act<<<gemm_big, blk, 0, stream>>>(xin, proj_w, proj_b, xout, BS_, D_, 3 * E_, 0);
    pe_add<<<BS_, blk, 0, stream>>>(xout);

    // 2) transformer layers
    for (int l = 0; l < L_; ++l) {
        const float* wq_l = wq + (size_t)l * D_ * D_;
        const float* wk_l = wk + (size_t)l * D_ * D_;
        const float* wv_l = wv + (size_t)l * D_ * D_;
        const float* wo_l = wo + (size_t)l * D_ * D_;
        gemm_bias_act<<<gemm_big, blk, 0, stream>>>(xout, wq_l, bq + l * D_, q, BS_, D_, D_, 0);
        gemm_bias_act<<<gemm_big, blk, 0, stream>>>(xout, wk_l, bk + l * D_, k, BS_, D_, D_, 0);
        gemm_bias_act<<<gemm_big, blk, 0, stream>>>(xout, wv_l, bv + l * D_, v, BS_, D_, D_, 0);
        rel_gather<<<(S_ * S_ * DK_ + 255) / 256, blk, 0, stream>>>(
            rel_table + (size_t)l * 5 * DK_, relation_mat, rel);
        attn_kernel<<<B_ * H_, blk, 0, stream>>>(q, k, v, rel, ctx);
        gemm_bias_act<<<gemm_big, blk, 0, stream>>>(ctx, wo_l, bo + l * D_, xin, BS_, D_, D_, 0);
        add_ln<<<BS_, blk, 0, stream>>>(xin, xout, aln_g + l * D_, aln_b + l * D_, xout);
        dim3 gff1((FF_ + 63) / 64, BS_ / 64);
        gemm_bias_act<<<gff1, blk, 0, stream>>>(xout, f_w1 + (size_t)l * D_ * FF_, f_b1 + l * FF_,
                                                ff, BS_, FF_, D_, 1);
        gemm_bias_act<<<gemm_big, blk, 0, stream>>>(ff, f_w2 + (size_t)l * FF_ * D_, f_b2 + l * D_,
                                                    xin, BS_, D_, FF_, 0);
        add_ln<<<BS_, blk, 0, stream>>>(xin, xout, ln_g + l * D_, ln_b + l * D_, xout);
    }

    // 3) user cross-attention
    gather_user<<<B_, blk, 0, stream>>>(user_table, user_ids, user_emb);
    dim3 gemm_small((D_ + 63) / 64, B_ / 64);       // M=128, N=1024
    gemm_bias_act<<<gemm_small, blk, 0, stream>>>(user_emb, mq_w, mq_b, q, B_, D_, D_, 0);
    gemm_bias_act<<<gemm_big, blk, 0, stream>>>(xout, mk_w, mk_b, k, BS_, D_, D_, 0);
    gemm_bias_act<<<gemm_big, blk, 0, stream>>>(xout, mv_w, mv_b, v, BS_, D_, D_, 0);
    cross_attn<<<B_ * H_, dim3(64), 0, stream>>>(q, k, v, up_pre);
    gemm_bias_act<<<gemm_small, blk, 0, stream>>>(up_pre, mo_w, mo_b, upref, B_, D_, D_, 0);

    // 4) sequence mean + concats
    seq_mean<<<B_, blk, 0, stream>>>(xout, seq);
    copy_cols<<<B_, blk, 0, stream>>>(upref, ci, D_, 2 * D_, 0);
    copy_cols<<<B_, blk, 0, stream>>>(seq,   ci, D_, 2 * D_, D_);
    copy_cols<<<B_, blk, 0, stream>>>(user_emb, ri, D_, 3 * D_, 0);
    copy_cols<<<B_, blk, 0, stream>>>(upref,    ri, D_, 3 * D_, D_);
    copy_cols<<<B_, blk, 0, stream>>>(seq,      ri, D_, 3 * D_, 2 * D_);

    // 5) heads
    // completion
    gemm_bias_act<<<gemm_small, blk, 0, stream>>>(ci, c_w1, c_b1, h1, B_, D_, 2 * D_, 1);
    gemm_bias_act<<<dim3(1, B_ / 64), blk, 0, stream>>>(h1, c_w2, c_b2, comp, B_, 1, D_, 2);
    // next logits
    gemm_bias_act<<<gemm_small, blk, 0, stream>>>(ci, n_w1, n_b1, h1, B_, D_, 2 * D_, 1);
    gemm_bias_act<<<dim3((V_ + 63) / 64, B_ / 64), blk, 0, stream>>>(h1, n_w2, n_b2, logits, B_, V_, D_, 0);
    // rating
    gemm_bias_act<<<gemm_small, blk, 0, stream>>>(ri, r_w1, r_b1, h1, B_, D_, 3 * D_, 1);
    gemm_bias_act<<<dim3(1, B_ / 64), blk, 0, stream>>>(h1, r_w2, r_b2, rating, B_, 1, D_, 0);
    // order
    gemm_bias_act<<<dim3((512 + 63) / 64, B_ / 64), blk, 0, stream>>>(upref, o_w1, o_b1, ho, B_, 512, D_, 1);
    gemm_bias_act<<<dim3(1, B_ / 64), blk, 0, stream>>>(ho, o_w2, o_b2, h1, B_, 2, 512, 0);
    order_softmax<<<1, dim3(128), 0, stream>>>(h1, order);
}

// Round 3
// 4911.280 us; speedup vs baseline: 2.5236x; 2.5236x over previous
//
#include <hip/hip_runtime.h>
#include <hip/hip_bf16.h>
#include <math.h>

// ---------------- problem constants ----------------
#define B_   128
#define S_   50
#define BS_  (B_*S_)        // 6400
#define E_   512
#define D_   1024
#define H_   16
#define DK_  64
#define L_   4
#define FF_  4096
#define V_   100000

typedef short bf8_t __attribute__((ext_vector_type(8)));
typedef float f32x4 __attribute__((ext_vector_type(4)));

__device__ __forceinline__ float gelu_exact(float x) {
    return 0.5f * x * (1.0f + erff(x * 0.70710678118654752440f));
}

// fp32 -> bf16 bits, round-to-nearest-even
__device__ __forceinline__ unsigned short f2bf(float f) {
    unsigned int u = __float_as_uint(f);
    return (unsigned short)((u + 0x7FFFu + ((u >> 16) & 1u)) >> 16);
}

// ---------------- embedding gather + concat ----------------
__global__ __launch_bounds__(256) void embed_concat(
    const float* __restrict__ mt, const float* __restrict__ ft, const float* __restrict__ et,
    const int* __restrict__ mids, const int* __restrict__ fids, const int* __restrict__ eids,
    float* __restrict__ xin)
{
    int bs = blockIdx.x;
    int mid = mids[bs], fid = fids[bs], eid = eids[bs];
    const float* srcs[3] = { mt + (size_t)mid * E_, ft + (size_t)fid * E_, et + (size_t)eid * E_ };
    float* dst = xin + (size_t)bs * (3 * E_);
    for (int i = threadIdx.x; i < 384; i += 256) {       // 384 float4 = 1536 floats
        int seg = i >> 7, off = i & 127;
        reinterpret_cast<float4*>(dst + seg * E_)[off] =
            reinterpret_cast<const float4*>(srcs[seg])[off];
    }
}

// ---------------- positional encoding add ----------------
__global__ __launch_bounds__(256) void pe_add(float* __restrict__ x)
{
    int row = blockIdx.x;
    int s = row % S_;
    float* px = x + (size_t)row * D_;
    const float c = -logf(10000.0f) / 512.0f;
    for (int d = threadIdx.x; d < D_; d += 256) {
        int second = d >= 512;
        int cc = second ? d - 512 : d;
        int i = cc >> 1;
        float div = expf(c * (float)(2 * i));
        float a = (float)s * div * (second ? 1.5f : 1.0f);
        float pe = (cc & 1) ? cosf(a) : sinf(a);
        px[d] += pe;
    }
}

// ---------------- bf16-MFMA GEMM: C = A[M,K] @ W[K,N] + bias, act ----------------
// fp32 in/out; operands converted to bf16 (RNE) during LDS staging.
// Requires M % 128 == 0, K % 32 == 0. N arbitrary (tail-guarded).
// 256 threads = 4 waves in 2x2, each wave owns a 64x64 output sub-tile.
__global__ __launch_bounds__(256) void gemm_mfma(
    const float* __restrict__ A, const float* __restrict__ W,
    const float* __restrict__ bias, float* __restrict__ C,
    int M, int N, int K, int act)
{
    __shared__ unsigned short As[128][40];   // [row][k], stride 80B (16B aligned)
    __shared__ unsigned short Bs[128][40];   // [col][k] (transposed W tile)
    const int tid  = threadIdx.x;
    const int lane = tid & 63;
    const int wid  = tid >> 6;
    const int wr   = wid >> 1, wc = wid & 1;
    const int rowBase = blockIdx.y * 128;
    const int colBase = blockIdx.x * 128;

    const int a_r = tid >> 1;            // 0..127 (tile row)
    const int a_h = (tid & 1) << 4;      // k offset 0 or 16
    const int b_c = tid & 127;           // 0..127 (tile col)
    const int b_h = (tid >> 7) << 4;     // k offset 0 or 16

    const int fr = lane & 15;            // fragment row/col
    const int fk = (lane >> 4) << 3;     // fragment k offset 0/8/16/24

    f32x4 acc[4][4] = {};
    const int nvalid = N - colBase;

    for (int kb = 0; kb < K; kb += 32) {
        // stage A tile (128x32) fp32 -> bf16
        const float* Ap = A + (size_t)(rowBase + a_r) * K + kb + a_h;
        #pragma unroll
        for (int q = 0; q < 4; ++q) {
            float4 v = *reinterpret_cast<const float4*>(Ap + q * 4);
            ushort4 bb;
            bb.x = f2bf(v.x); bb.y = f2bf(v.y); bb.z = f2bf(v.z); bb.w = f2bf(v.w);
            *reinterpret_cast<ushort4*>(&As[a_r][a_h + q * 4]) = bb;
        }
        // stage B tile (32x128) transposed: Bs[col][k] = bf16(W[kb+k][colBase+col])
        {
            unsigned short tmp[16];
            const float* Wp = W + (size_t)(kb + b_h) * N + colBase + b_c;
            bool valid = (b_c < nvalid);
            #pragma unroll
            for (int kk2 = 0; kk2 < 16; ++kk2) {
                float v = valid ? Wp[(size_t)kk2 * N] : 0.0f;
                tmp[kk2] = f2bf(v);
            }
            #pragma unroll
            for (int h2 = 0; h2 < 2; ++h2)
                *reinterpret_cast<bf8_t*>(&Bs[b_c][b_h + h2 * 8]) =
                    *reinterpret_cast<const bf8_t*>(&tmp[h2 * 8]);
        }
        __syncthreads();

        bf8_t af[4], bfv[4];
        #pragma unroll
        for (int m = 0; m < 4; ++m)
            af[m] = *reinterpret_cast<const bf8_t*>(&As[wr * 64 + m * 16 + fr][fk]);
        #pragma unroll
        for (int n = 0; n < 4; ++n)
            bfv[n] = *reinterpret_cast<const bf8_t*>(&Bs[wc * 64 + n * 16 + fr][fk]);
        #pragma unroll
        for (int m = 0; m < 4; ++m)
            #pragma unroll
            for (int n = 0; n < 4; ++n)
                acc[m][n] = __builtin_amdgcn_mfma_f32_16x16x32_bf16(af[m], bfv[n], acc[m][n], 0, 0, 0);
        __syncthreads();
    }

    // epilogue: C/D map col=lane&15, row=(lane>>4)*4+reg
    const int orow = (lane >> 4) << 2;
    #pragma unroll
    for (int m = 0; m < 4; ++m) {
        int r0 = rowBase + wr * 64 + m * 16 + orow;
        #pragma unroll
        for (int n = 0; n < 4; ++n) {
            int c = colBase + wc * 64 + n * 16 + fr;
            if (c < N) {
                float bv = bias ? bias[c] : 0.0f;
                #pragma unroll
                for (int r = 0; r < 4; ++r) {
                    float v = acc[m][n][r] + bv;
                    if (act == 1) v = gelu_exact(v);
                    else if (act == 2) v = 1.0f / (1.0f + expf(-v));
                    C[(size_t)(r0 + r) * N + c] = v;
                }
            }
        }
    }
}

// ---------------- fp32 tiled GEMM (only for tiny-N head layers) ----------------
__global__ __launch_bounds__(256) void gemm_bias_act(
    const float* __restrict__ A, const float* __restrict__ W,
    const float* __restrict__ bias, float* __restrict__ C,
    int M, int N, int K, int act)
{
    __shared__ float As[16][64];
    __shared__ float Bs[16][68];
    const int tid = threadIdx.x;
    const int rowBase = blockIdx.y * 64;
    const int colBase = blockIdx.x * 64;
    const int tx = tid & 15, ty = tid >> 4;
    const int arow = tid >> 2;
    const int ak4  = (tid & 3) << 2;
    const int brow = tid >> 4;
    const int bn4  = (tid & 15) << 2;
    const bool fullN = (colBase + 64 <= N);

    float acc[4][4] = {};

    for (int kb = 0; kb < K; kb += 16) {
        float4 av = *reinterpret_cast<const float4*>(&A[(size_t)(rowBase + arow) * K + kb + ak4]);
        As[ak4 + 0][arow] = av.x;
        As[ak4 + 1][arow] = av.y;
        As[ak4 + 2][arow] = av.z;
        As[ak4 + 3][arow] = av.w;
        if (fullN) {
            float4 bv = *reinterpret_cast<const float4*>(&W[(size_t)(kb + brow) * N + colBase + bn4]);
            *reinterpret_cast<float4*>(&Bs[brow][bn4]) = bv;
        } else {
            #pragma unroll
            for (int t = 0; t < 4; ++t) {
                int n = colBase + bn4 + t;
                Bs[brow][bn4 + t] = (n < N) ? W[(size_t)(kb + brow) * N + n] : 0.0f;
            }
        }
        __syncthreads();
        #pragma unroll
        for (int kk = 0; kk < 16; ++kk) {
            float4 a4 = *reinterpret_cast<const float4*>(&As[kk][ty << 2]);
            float4 b4 = *reinterpret_cast<const float4*>(&Bs[kk][tx << 2]);
            float ar[4] = { a4.x, a4.y, a4.z, a4.w };
            float br[4] = { b4.x, b4.y, b4.z, b4.w };
            #pragma unroll
            for (int i = 0; i < 4; ++i)
                #pragma unroll
                for (int j = 0; j < 4; ++j)
                    acc[i][j] += ar[i] * br[j];
        }
        __syncthreads();
    }

    #pragma unroll
    for (int i = 0; i < 4; ++i) {
        int r = rowBase + (ty << 2) + i;
        #pragma unroll
        for (int j = 0; j < 4; ++j) {
            int c = colBase + (tx << 2) + j;
            if (c < N) {
                float v = acc[i][j] + (bias ? bias[c] : 0.0f);
                if (act == 1) v = gelu_exact(v);
                else if (act == 2) v = 1.0f / (1.0f + expf(-v));
                C[(size_t)r * N + c] = v;
            }
        }
    }
}

// ---------------- rel gather ----------------
__global__ __launch_bounds__(256) void rel_gather(
    const float* __restrict__ rt, const int* __restrict__ rm, float* __restrict__ rel)
{
    int idx = blockIdx.x * 256 + threadIdx.x;
    if (idx >= S_ * S_ * DK_) return;
    int d = idx & 63;
    int ij = idx >> 6;
    rel[idx] = rt[(size_t)rm[ij] * DK_ + d];
}

// ---------------- self-attention (per (b,h) block) ----------------
__global__ __launch_bounds__(256) void attn_kernel(
    const float* __restrict__ q, const float* __restrict__ k, const float* __restrict__ v,
    const float* __restrict__ rel, float* __restrict__ ctx)
{
    int bh = blockIdx.x;
    int b = bh >> 4, h = bh & 15;
    __shared__ float qs[S_][DK_], ks[S_][DK_], vs[S_][DK_];
    int tid = threadIdx.x;
    int wave = tid >> 6, lane = tid & 63;

    for (int idx = tid; idx < S_ * DK_; idx += 256) {
        int s = idx >> 6, d = idx & 63;
        size_t g = ((size_t)(b * S_ + s)) * D_ + h * DK_ + d;
        qs[s][d] = q[g];
        ks[s][d] = k[g];
        vs[s][d] = v[g];
    }
    __syncthreads();

    const float scale = 0.125f;
    for (int i = wave; i < S_; i += 4) {
        float sc = -INFINITY;
        if (lane < S_) {
            float acc = 0.0f, accr = 0.0f;
            const float* rrow = rel + ((size_t)i * S_ + lane) * DK_;
            #pragma unroll 8
            for (int d = 0; d < DK_; ++d) {
                float qd = qs[i][d];
                acc  += qd * ks[lane][d];
                accr += qd * rrow[d];
            }
            sc = acc * scale + 0.5f * accr;
        }
        float m = sc;
        #pragma unroll
        for (int off = 32; off; off >>= 1) m = fmaxf(m, __shfl_xor(m, off));
        float e = (lane < S_) ? expf(sc - m) : 0.0f;
        float sum = e;
        #pragma unroll
        for (int off = 32; off; off >>= 1) sum += __shfl_xor(sum, off);
        float aval = e / sum;

        float acc = 0.0f;
        for (int j = 0; j < S_; ++j) {
            float aj = __shfl(aval, j);
            acc += aj * vs[j][lane];
        }
        ctx[((size_t)(b * S_ + i)) * D_ + h * DK_ + lane] = acc;
    }
}

// ---------------- add + layernorm ----------------
__global__ __launch_bounds__(256) void add_ln(
    const float* __restrict__ a, const float* __restrict__ res,
    const float* __restrict__ g, const float* __restrict__ be,
    float* __restrict__ out)
{
    int row = blockIdx.x, tid = threadIdx.x;
    const float* pa = a + (size_t)row * D_;
    const float* pr = res + (size_t)row * D_;
    float vals[4];
    float s = 0.0f;
    #pragma unroll
    for (int t = 0; t < 4; ++t) {
        float v = pa[tid + t * 256] + pr[tid + t * 256];
        vals[t] = v;
        s += v;
    }
    __shared__ float red[8];
    #pragma unroll
    for (int off = 32; off; off >>= 1) s += __shfl_xor(s, off);
    int wave = tid >> 6, lane = tid & 63;
    if (lane == 0) red[wave] = s;
    __syncthreads();
    float mean = (red[0] + red[1] + red[2] + red[3]) * (1.0f / D_);
    float vs = 0.0f;
    #pragma unroll
    for (int t = 0; t < 4; ++t) {
        float d = vals[t] - mean;
        vs += d * d;
    }
    #pragma unroll
    for (int off = 32; off; off >>= 1) vs += __shfl_xor(vs, off);
    if (lane == 0) red[4 + wave] = vs;
    __syncthreads();
    float var = (red[4] + red[5] + red[6] + red[7]) * (1.0f / D_);
    float rstd = rsqrtf(var + 1e-5f);
    float* po = out + (size_t)row * D_;
    #pragma unroll
    for (int t = 0; t < 4; ++t) {
        int c = tid + t * 256;
        po[c] = (vals[t] - mean) * rstd * g[c] + be[c];
    }
}

// ---------------- user embedding gather ----------------
__global__ __launch_bounds__(256) void gather_user(
    const float* __restrict__ ut, const int* __restrict__ ids, float* __restrict__ out)
{
    int b = blockIdx.x;
    int uid = ids[b];
    for (int d = threadIdx.x; d < D_; d += 256)
        out[(size_t)b * D_ + d] = ut[(size_t)uid * D_ + d];
}

// ---------------- cross attention (q_len = 1) ----------------
__global__ __launch_bounds__(64) void cross_attn(
    const float* __restrict__ qh, const float* __restrict__ kh, const float* __restrict__ vh,
    float* __restrict__ up)
{
    int bh = blockIdx.x;
    int b = bh >> 4, h = bh & 15;
    int lane = threadIdx.x;
    __shared__ float qv[DK_];
    qv[lane] = qh[(size_t)b * D_ + h * DK_ + lane];
    __syncthreads();
    float sc = -INFINITY;
    if (lane < S_) {
        float acc = 0.0f;
        const float* krow = kh + ((size_t)(b * S_ + lane)) * D_ + h * DK_;
        #pragma unroll 8
        for (int d = 0; d < DK_; ++d) acc += qv[d] * krow[d];
        sc = acc * 0.125f;
    }
    float m = sc;
    #pragma unroll
    for (int off = 32; off; off >>= 1) m = fmaxf(m, __shfl_xor(m, off));
    float e = (lane < S_) ? expf(sc - m) : 0.0f;
    float sum = e;
    #pragma unroll
    for (int off = 32; off; off >>= 1) sum += __shfl_xor(sum, off);
    float aval = e / sum;
    float acc = 0.0f;
    for (int j = 0; j < S_; ++j) {
        float aj = __shfl(aval, j);
        acc += aj * vh[((size_t)(b * S_ + j)) * D_ + h * DK_ + lane];
    }
    up[(size_t)b * D_ + h * DK_ + lane] = acc;
}

// ---------------- sequence mean ----------------
__global__ __launch_bounds__(256) void seq_mean(const float* __restrict__ x, float* __restrict__ out)
{
    int b = blockIdx.x;
    for (int d = threadIdx.x; d < D_; d += 256) {
        float s = 0.0f;
        for (int si = 0; si < S_; ++si)
            s += x[((size_t)(b * S_ + si)) * D_ + d];
        out[(size_t)b * D_ + d] = s * (1.0f / S_);
    }
}

// ---------------- column copy (for concat) ----------------
__global__ __launch_bounds__(256) void copy_cols(
    const float* __restrict__ src, float* __restrict__ dst,
    int width, int dstStride, int dstOff)
{
    int r = blockIdx.x;
    for (int c = threadIdx.x; c < width; c += 256)
        dst[(size_t)r * dstStride + dstOff + c] = src[(size_t)r * width + c];
}

// ---------------- order softmax ----------------
__global__ __launch_bounds__(128) void order_softmax(const float* __restrict__ in, float* __restrict__ out)
{
    int b = threadIdx.x;
    if (b >= B_) return;
    float a = in[b * 2], c = in[b * 2 + 1];
    float m = fmaxf(a, c);
    float ea = expf(a - m), ec = expf(c - m);
    float s = ea + ec;
    out[b * 2] = ea / s;
    out[b * 2 + 1] = ec / s;
}

// ---------------- host-side launcher ----------------
extern "C" void kernel_launch(void* const* d_in, const int* in_sizes, int n_in,
                              void* d_out, int out_size, void* d_ws, size_t ws_size,
                              hipStream_t stream) {
    const float* movie_table = (const float*)d_in[0];
    const float* fran_table  = (const float*)d_in[1];
    const float* entry_table = (const float*)d_in[2];
    const float* proj_w      = (const float*)d_in[3];
    const float* proj_b      = (const float*)d_in[4];
    const float* wq          = (const float*)d_in[5];
    const float* bq          = (const float*)d_in[6];
    const float* wk          = (const float*)d_in[7];
    const float* bk          = (const float*)d_in[8];
    const float* wv          = (const float*)d_in[9];
    const float* bv          = (const float*)d_in[10];
    const float* wo          = (const float*)d_in[11];
    const float* bo          = (const float*)d_in[12];
    const float* rel_table   = (const float*)d_in[13];
    const float* aln_g       = (const float*)d_in[14];
    const float* aln_b       = (const float*)d_in[15];
    const float* f_w1        = (const float*)d_in[16];
    const float* f_b1        = (const float*)d_in[17];
    const float* f_w2        = (const float*)d_in[18];
    const float* f_b2        = (const float*)d_in[19];
    const float* ln_g        = (const float*)d_in[20];
    const float* ln_b        = (const float*)d_in[21];
    const float* user_table  = (const float*)d_in[22];
    const float* mq_w        = (const float*)d_in[23];
    const float* mq_b        = (const float*)d_in[24];
    const float* mk_w        = (const float*)d_in[25];
    const float* mk_b        = (const float*)d_in[26];
    const float* mv_w        = (const float*)d_in[27];
    const float* mv_b        = (const float*)d_in[28];
    const float* mo_w        = (const float*)d_in[29];
    const float* mo_b        = (const float*)d_in[30];
    const float* c_w1        = (const float*)d_in[31];
    const float* c_b1        = (const float*)d_in[32];
    const float* c_w2        = (const float*)d_in[33];
    const float* c_b2        = (const float*)d_in[34];
    const float* n_w1        = (const float*)d_in[35];
    const float* n_b1        = (const float*)d_in[36];
    const float* n_w2        = (const float*)d_in[37];
    const float* n_b2        = (const float*)d_in[38];
    const float* r_w1        = (const float*)d_in[39];
    const float* r_b1        = (const float*)d_in[40];
    const float* r_w2        = (const float*)d_in[41];
    const float* r_b2        = (const float*)d_in[42];
    const float* o_w1        = (const float*)d_in[43];
    const float* o_b1        = (const float*)d_in[44];
    const float* o_w2        = (const float*)d_in[45];
    const float* o_b2        = (const float*)d_in[46];
    const int* user_ids      = (const int*)d_in[47];
    const int* movie_ids     = (const int*)d_in[48];
    const int* franchise_ids = (const int*)d_in[49];
    const int* entry_types   = (const int*)d_in[50];
    const int* relation_mat  = (const int*)d_in[51];

    // ---- workspace layout (floats) ----
    float* ws = (float*)d_ws;
    float* xin      = ws;                        // BS*1536
    float* q        = xin + (size_t)BS_ * 1536;  // BS*D
    float* k        = q   + (size_t)BS_ * D_;
    float* v        = k   + (size_t)BS_ * D_;
    float* ctx      = v   + (size_t)BS_ * D_;
    float* ff       = ctx + (size_t)BS_ * D_;    // BS*FF
    float* rel      = ff  + (size_t)BS_ * FF_;   // S*S*DK
    float* user_emb = rel + (size_t)S_ * S_ * DK_;
    float* up_pre   = user_emb + (size_t)B_ * D_;
    float* seq      = up_pre   + (size_t)B_ * D_;
    float* ci       = seq      + (size_t)B_ * D_;     // B * 2D
    float* ri       = ci       + (size_t)B_ * 2 * D_; // B * 3D
    float* h1       = ri       + (size_t)B_ * 3 * D_; // B * D
    float* ho       = h1       + (size_t)B_ * D_;     // B * 512

    // ---- d_out layout ----
    float* xout    = (float*)d_out;                 // [BS, D]
    float* comp    = xout + (size_t)BS_ * D_;       // [B,1]
    float* logits  = comp + B_;                     // [B,V]
    float* rating  = logits + (size_t)B_ * V_;      // [B,1]
    float* order   = rating + B_;                   // [B,2]
    float* upref   = order + 2 * B_;                // [B,D]

    dim3 blk(256);
    dim3 g_1024(8, BS_ / 128);                      // N=1024, M=6400
    dim3 g_ff1(32, BS_ / 128);                      // N=4096
    dim3 g_small(8, 1);                             // M=128, N=1024

    // 1) embeddings + projection + PE
    embed_concat<<<BS_, blk, 0, stream>>>(movie_table, fran_table, entry_table,
                                          movie_ids, franchise_ids, entry_types, xin);
    gemm_mfma<<<g_1024, blk, 0, stream>>>(xin, proj_w, proj_b, xout, BS_, D_, 3 * E_, 0);
    pe_add<<<BS_, blk, 0, stream>>>(xout);

    // 2) transformer layers
    for (int l = 0; l < L_; ++l) {
        const float* wq_l = wq + (size_t)l * D_ * D_;
        const float* wk_l = wk + (size_t)l * D_ * D_;
        const float* wv_l = wv + (size_t)l * D_ * D_;
        const float* wo_l = wo + (size_t)l * D_ * D_;
        gemm_mfma<<<g_1024, blk, 0, stream>>>(xout, wq_l, bq + l * D_, q, BS_, D_, D_, 0);
        gemm_mfma<<<g_1024, blk, 0, stream>>>(xout, wk_l, bk + l * D_, k, BS_, D_, D_, 0);
        gemm_mfma<<<g_1024, blk, 0, stream>>>(xout, wv_l, bv + l * D_, v, BS_, D_, D_, 0);
        rel_gather<<<(S_ * S_ * DK_ + 255) / 256, blk, 0, stream>>>(
            rel_table + (size_t)l * 5 * DK_, relation_mat, rel);
        attn_kernel<<<B_ * H_, blk, 0, stream>>>(q, k, v, rel, ctx);
        gemm_mfma<<<g_1024, blk, 0, stream>>>(ctx, wo_l, bo + l * D_, xin, BS_, D_, D_, 0);
        add_ln<<<BS_, blk, 0, stream>>>(xin, xout, aln_g + l * D_, aln_b + l * D_, xout);
        gemm_mfma<<<g_ff1, blk, 0, stream>>>(xout, f_w1 + (size_t)l * D_ * FF_, f_b1 + l * FF_,
                                             ff, BS_, FF_, D_, 1);
        gemm_mfma<<<g_1024, blk, 0, stream>>>(ff, f_w2 + (size_t)l * FF_ * D_, f_b2 + l * D_,
                                              xin, BS_, D_, FF_, 0);
        add_ln<<<BS_, blk, 0, stream>>>(xin, xout, ln_g + l * D_, ln_b + l * D_, xout);
    }

    // 3) user cross-attention
    gather_user<<<B_, blk, 0, stream>>>(user_table, user_ids, user_emb);
    gemm_mfma<<<g_small, blk, 0, stream>>>(user_emb, mq_w, mq_b, q, B_, D_, D_, 0);
    gemm_mfma<<<g_1024, blk, 0, stream>>>(xout, mk_w, mk_b, k, BS_, D_, D_, 0);
    gemm_mfma<<<g_1024, blk, 0, stream>>>(xout, mv_w, mv_b, v, BS_, D_, D_, 0);
    cross_attn<<<B_ * H_, dim3(64), 0, stream>>>(q, k, v, up_pre);
    gemm_mfma<<<g_small, blk, 0, stream>>>(up_pre, mo_w, mo_b, upref, B_, D_, D_, 0);

    // 4) sequence mean + concats
    seq_mean<<<B_, blk, 0, stream>>>(xout, seq);
    copy_cols<<<B_, blk, 0, stream>>>(upref, ci, D_, 2 * D_, 0);
    copy_cols<<<B_, blk, 0, stream>>>(seq,   ci, D_, 2 * D_, D_);
    copy_cols<<<B_, blk, 0, stream>>>(user_emb, ri, D_, 3 * D_, 0);
    copy_cols<<<B_, blk, 0, stream>>>(upref,    ri, D_, 3 * D_, D_);
    copy_cols<<<B_, blk, 0, stream>>>(seq,      ri, D_, 3 * D_, 2 * D_);

    // 5) heads
    // completion
    gemm_mfma<<<g_small, blk, 0, stream>>>(ci, c_w1, c_b1, h1, B_, D_, 2 * D_, 1);
    gemm_bias_act<<<dim3(1, B_ / 64), blk, 0, stream>>>(h1, c_w2, c_b2, comp, B_, 1, D_, 2);
    // next logits (V=100000 -> 782 col-blocks, tail guarded)
    gemm_mfma<<<g_small, blk, 0, stream>>>(ci, n_w1, n_b1, h1, B_, D_, 2 * D_, 1);
    gemm_mfma<<<dim3((V_ + 127) / 128, 1), blk, 0, stream>>>(h1, n_w2, n_b2, logits, B_, V_, D_, 0);
    // rating
    gemm_mfma<<<g_small, blk, 0, stream>>>(ri, r_w1, r_b1, h1, B_, D_, 3 * D_, 1);
    gemm_bias_act<<<dim3(1, B_ / 64), blk, 0, stream>>>(h1, r_w2, r_b2, rating, B_, 1, D_, 0);
    // order
    gemm_mfma<<<dim3(4, 1), blk, 0, stream>>>(upref, o_w1, o_b1, ho, B_, 512, D_, 1);
    gemm_bias_act<<<dim3(1, B_ / 64), blk, 0, stream>>>(ho, o_w2, o_b2, h1, B_, 2, 512, 0);
    order_softmax<<<1, dim3(128), 0, stream>>>(h1, order);
}

// Round 4
// 2862.293 us; speedup vs baseline: 4.3302x; 1.7159x over previous
//
#include <hip/hip_runtime.h>
#include <hip/hip_bf16.h>
#include <math.h>

// ---------------- problem constants ----------------
#define B_   128
#define S_   50
#define BS_  (B_*S_)        // 6400
#define E_   512
#define D_   1024
#define H_   16
#define DK_  64
#define L_   4
#define FF_  4096
#define V_   100000

typedef short bf8_t __attribute__((ext_vector_type(8)));
typedef float f32x4 __attribute__((ext_vector_type(4)));
typedef unsigned short u16;

__device__ __forceinline__ float gelu_exact(float x) {
    return 0.5f * x * (1.0f + erff(x * 0.70710678118654752440f));
}
// fp32 -> bf16 bits, round-to-nearest-even
__device__ __forceinline__ u16 f2bf(float f) {
    unsigned int u = __float_as_uint(f);
    return (u16)((u + 0x7FFFu + ((u >> 16) & 1u)) >> 16);
}
__device__ __forceinline__ float bf2f(u16 u) {
    return __uint_as_float(((unsigned int)u) << 16);
}

// async global->LDS, 16B per lane (CK-style addrspace plumbing)
__device__ __forceinline__ void gload16(const u16* g, u16* l) {
    auto* g1 = reinterpret_cast<const __attribute__((address_space(1))) unsigned int*>(
                   reinterpret_cast<uintptr_t>(g));
    auto* l3 = reinterpret_cast<__attribute__((address_space(3))) unsigned int*>(
                   reinterpret_cast<uintptr_t>(l));
    __builtin_amdgcn_global_load_lds(g1, l3, 16, 0, 0);
}

// ---------------- weight convert+transpose: Wt[n][k] = bf16(W[k][n]) ----------------
__global__ __launch_bounds__(256) void wtrans(
    const float* __restrict__ W, u16* __restrict__ Wt,
    int K, int N, long srcLS, long dstLS, int dstRowOff)
{
    __shared__ float t[32][33];
    int nb = blockIdx.x * 32, kb = blockIdx.y * 32, l = blockIdx.z;
    W  += (size_t)l * srcLS;
    Wt += (size_t)l * dstLS;
    int c = threadIdx.x & 31, r0 = threadIdx.x >> 5;  // r0 in 0..7
    #pragma unroll
    for (int rr = 0; rr < 32; rr += 8)
        t[rr + r0][c] = W[(size_t)(kb + rr + r0) * N + nb + c];
    __syncthreads();
    #pragma unroll
    for (int rr = 0; rr < 32; rr += 8)
        Wt[(size_t)(dstRowOff + nb + rr + r0) * K + kb + c] = f2bf(t[c][rr + r0]);
}

// ---------------- embedding gather + concat (bf16 out) ----------------
__global__ __launch_bounds__(256) void embed_concat(
    const float* __restrict__ mt, const float* __restrict__ ft, const float* __restrict__ et,
    const int* __restrict__ mids, const int* __restrict__ fids, const int* __restrict__ eids,
    u16* __restrict__ xinb)
{
    int bs = blockIdx.x;
    int mid = mids[bs], fid = fids[bs], eid = eids[bs];
    const float* srcs[3] = { mt + (size_t)mid * E_, ft + (size_t)fid * E_, et + (size_t)eid * E_ };
    u16* dst = xinb + (size_t)bs * (3 * E_);
    for (int i = threadIdx.x; i < 384; i += 256) {       // 384 float4 = 1536 floats
        int seg = i >> 7, off = i & 127;
        float4 v = reinterpret_cast<const float4*>(srcs[seg])[off];
        ushort4 b;
        b.x = f2bf(v.x); b.y = f2bf(v.y); b.z = f2bf(v.z); b.w = f2bf(v.w);
        reinterpret_cast<ushort4*>(dst + seg * E_)[off] = b;
    }
}

// ---------------- positional encoding table [50][1024] ----------------
__global__ __launch_bounds__(256) void pe_table(float* __restrict__ pet)
{
    int s = blockIdx.x;
    const float c = -logf(10000.0f) / 512.0f;
    for (int d = threadIdx.x; d < D_; d += 256) {
        int second = d >= 512;
        int cc = second ? d - 512 : d;
        int i = cc >> 1;
        float div = expf(c * (float)(2 * i));
        float a = (float)s * div * (second ? 1.5f : 1.0f);
        pet[s * D_ + d] = (cc & 1) ? cosf(a) : sinf(a);
    }
}

// x += PE; write fp32 (d_out x) + bf16 copy
__global__ __launch_bounds__(256) void pe_apply(
    float* __restrict__ x, const float* __restrict__ pet, u16* __restrict__ xb)
{
    int row = blockIdx.x;
    int s = row % S_;
    for (int d = threadIdx.x; d < D_; d += 256) {
        float v = x[(size_t)row * D_ + d] + pet[s * D_ + d];
        x[(size_t)row * D_ + d] = v;
        xb[(size_t)row * D_ + d] = f2bf(v);
    }
}

// ---------------- bf16 MFMA GEMM (m97-style, global_load_lds staging) ----------------
// A bf16 [M,K] row-major, Wt bf16 [N,K] row-major, bias fp32[N].
// M%128==0, N%128==0, K%32==0. Cf (fp32) and/or Cb (bf16) outputs.
__global__ __launch_bounds__(256) void gemm_bf16(
    const u16* __restrict__ A, const u16* __restrict__ Wt,
    const float* __restrict__ bias, float* __restrict__ Cf, u16* __restrict__ Cb,
    int M, int N, int K, int act)
{
    __shared__ u16 As[128 * 32];
    __shared__ u16 Bs[128 * 32];
    const int tid  = threadIdx.x;
    const int lane = tid & 63;
    const int wid  = tid >> 6;
    const int wr   = wid >> 1, wc = wid & 1;
    const int rowBase = blockIdx.y * 128;
    const int colBase = blockIdx.x * 128;
    const int fr = lane & 15;
    const int fk = (lane >> 4) << 3;

    // staging: wave wid covers tile rows [wid*32, wid*32+32); 16 rows per gload inst
    const int sRow = (wid << 5) + (lane >> 2);
    const int sCol = (lane & 3) << 3;
    const u16* aSrc = A  + (size_t)(rowBase + sRow) * K + sCol;
    const u16* bSrc = Wt + (size_t)(colBase + sRow) * K + sCol;
    u16* aDst = &As[(wid << 5) << 5];
    u16* bDst = &Bs[(wid << 5) << 5];

    f32x4 acc[4][4] = {};

    for (int kb = 0; kb < K; kb += 32) {
        gload16(aSrc + kb,                 aDst);
        gload16(aSrc + kb + (size_t)16 * K, aDst + 16 * 32);
        gload16(bSrc + kb,                 bDst);
        gload16(bSrc + kb + (size_t)16 * K, bDst + 16 * 32);
        __syncthreads();

        bf8_t af[4], bf[4];
        #pragma unroll
        for (int m = 0; m < 4; ++m)
            af[m] = *reinterpret_cast<const bf8_t*>(&As[(wr * 64 + m * 16 + fr) * 32 + fk]);
        #pragma unroll
        for (int n = 0; n < 4; ++n)
            bf[n] = *reinterpret_cast<const bf8_t*>(&Bs[(wc * 64 + n * 16 + fr) * 32 + fk]);
        #pragma unroll
        for (int m = 0; m < 4; ++m)
            #pragma unroll
            for (int n = 0; n < 4; ++n)
                acc[m][n] = __builtin_amdgcn_mfma_f32_16x16x32_bf16(af[m], bf[n], acc[m][n], 0, 0, 0);
        __syncthreads();
    }

    const int orow = (lane >> 4) << 2;
    #pragma unroll
    for (int m = 0; m < 4; ++m) {
        int r0 = rowBase + wr * 64 + m * 16 + orow;
        #pragma unroll
        for (int n = 0; n < 4; ++n) {
            int c = colBase + wc * 64 + n * 16 + fr;
            float bv = bias ? bias[c] : 0.0f;
            #pragma unroll
            for (int r = 0; r < 4; ++r) {
                float v = acc[m][n][r] + bv;
                if (act == 1) v = gelu_exact(v);
                if (Cf) Cf[(size_t)(r0 + r) * N + c] = v;
                if (Cb) Cb[(size_t)(r0 + r) * N + c] = f2bf(v);
            }
        }
    }
}

// ---------------- fp32-input MFMA GEMM (logits: W streamed fp32) ----------------
__global__ __launch_bounds__(256) void gemm_mfma(
    const float* __restrict__ A, const float* __restrict__ W,
    const float* __restrict__ bias, float* __restrict__ C,
    int M, int N, int K, int act)
{
    __shared__ u16 As[128][40];
    __shared__ u16 Bs[128][40];
    const int tid  = threadIdx.x;
    const int lane = tid & 63;
    const int wid  = tid >> 6;
    const int wr   = wid >> 1, wc = wid & 1;
    const int rowBase = blockIdx.y * 128;
    const int colBase = blockIdx.x * 128;

    const int a_r = tid >> 1;
    const int a_h = (tid & 1) << 4;
    const int b_c = tid & 127;
    const int b_h = (tid >> 7) << 4;

    const int fr = lane & 15;
    const int fk = (lane >> 4) << 3;

    f32x4 acc[4][4] = {};
    const int nvalid = N - colBase;

    for (int kb = 0; kb < K; kb += 32) {
        const float* Ap = A + (size_t)(rowBase + a_r) * K + kb + a_h;
        #pragma unroll
        for (int q = 0; q < 4; ++q) {
            float4 v = *reinterpret_cast<const float4*>(Ap + q * 4);
            ushort4 bb;
            bb.x = f2bf(v.x); bb.y = f2bf(v.y); bb.z = f2bf(v.z); bb.w = f2bf(v.w);
            *reinterpret_cast<ushort4*>(&As[a_r][a_h + q * 4]) = bb;
        }
        {
            u16 tmp[16];
            const float* Wp = W + (size_t)(kb + b_h) * N + colBase + b_c;
            bool valid = (b_c < nvalid);
            #pragma unroll
            for (int kk2 = 0; kk2 < 16; ++kk2) {
                float v = valid ? Wp[(size_t)kk2 * N] : 0.0f;
                tmp[kk2] = f2bf(v);
            }
            #pragma unroll
            for (int h2 = 0; h2 < 2; ++h2)
                *reinterpret_cast<bf8_t*>(&Bs[b_c][b_h + h2 * 8]) =
                    *reinterpret_cast<const bf8_t*>(&tmp[h2 * 8]);
        }
        __syncthreads();

        bf8_t af[4], bfv[4];
        #pragma unroll
        for (int m = 0; m < 4; ++m)
            af[m] = *reinterpret_cast<const bf8_t*>(&As[wr * 64 + m * 16 + fr][fk]);
        #pragma unroll
        for (int n = 0; n < 4; ++n)
            bfv[n] = *reinterpret_cast<const bf8_t*>(&Bs[wc * 64 + n * 16 + fr][fk]);
        #pragma unroll
        for (int m = 0; m < 4; ++m)
            #pragma unroll
            for (int n = 0; n < 4; ++n)
                acc[m][n] = __builtin_amdgcn_mfma_f32_16x16x32_bf16(af[m], bfv[n], acc[m][n], 0, 0, 0);
        __syncthreads();
    }

    const int orow = (lane >> 4) << 2;
    #pragma unroll
    for (int m = 0; m < 4; ++m) {
        int r0 = rowBase + wr * 64 + m * 16 + orow;
        #pragma unroll
        for (int n = 0; n < 4; ++n) {
            int c = colBase + wc * 64 + n * 16 + fr;
            if (c < N) {
                float bv = bias ? bias[c] : 0.0f;
                #pragma unroll
                for (int r = 0; r < 4; ++r) {
                    float v = acc[m][n][r] + bv;
                    if (act == 1) v = gelu_exact(v);
                    else if (act == 2) v = 1.0f / (1.0f + expf(-v));
                    C[(size_t)(r0 + r) * N + c] = v;
                }
            }
        }
    }
}

// ---------------- self-attention (per (b,h) block), bf16 qkv merged [BS,3072] ----------------
// R-table trick: q.rel[i,j,:] = R[i, rm[i,j]], R = q @ rel_table^T (5 rel types)
__global__ __launch_bounds__(256) void attn_kernel(
    const u16* __restrict__ qkv, const float* __restrict__ rt, const int* __restrict__ rm,
    u16* __restrict__ ctxb)
{
    int bh = blockIdx.x;
    int b = bh >> 4, h = bh & 15;
    __shared__ float qs[S_][DK_ + 1], ks[S_][DK_ + 1], vs[S_][DK_ + 1];
    __shared__ float rts[5][DK_];
    __shared__ float Rs[S_][8];
    int tid = threadIdx.x;
    int wave = tid >> 6, lane = tid & 63;

    for (int idx = tid; idx < S_ * DK_; idx += 256) {
        int s = idx >> 6, d = idx & 63;
        size_t g = ((size_t)(b * S_ + s)) * (3 * D_) + h * DK_ + d;
        qs[s][d] = bf2f(qkv[g]);
        ks[s][d] = bf2f(qkv[g + D_]);
        vs[s][d] = bf2f(qkv[g + 2 * D_]);
    }
    for (int i = tid; i < 5 * DK_; i += 256)
        rts[i >> 6][i & 63] = rt[i];
    __syncthreads();

    for (int t = tid; t < S_ * 5; t += 256) {
        int i = t / 5, r = t - 5 * i;
        float a = 0.0f;
        #pragma unroll 8
        for (int d = 0; d < DK_; ++d) a += qs[i][d] * rts[r][d];
        Rs[i][r] = a;
    }
    __syncthreads();

    const float scale = 0.125f;
    for (int i = wave; i < S_; i += 4) {
        float sc = -INFINITY;
        if (lane < S_) {
            float acc = 0.0f;
            #pragma unroll 8
            for (int d = 0; d < DK_; ++d) acc += qs[i][d] * ks[lane][d];
            sc = acc * scale + 0.5f * Rs[i][rm[i * S_ + lane]];
        }
        float m = sc;
        #pragma unroll
        for (int off = 32; off; off >>= 1) m = fmaxf(m, __shfl_xor(m, off));
        float e = (lane < S_) ? expf(sc - m) : 0.0f;
        float sum = e;
        #pragma unroll
        for (int off = 32; off; off >>= 1) sum += __shfl_xor(sum, off);
        float aval = e / sum;

        float acc = 0.0f;
        for (int j = 0; j < S_; ++j) {
            float aj = __shfl(aval, j);
            acc += aj * vs[j][lane];
        }
        ctxb[((size_t)(b * S_ + i)) * D_ + h * DK_ + lane] = f2bf(acc);
    }
}

// ---------------- add + layernorm: out = LN(bf16(a) + res); writes fp32 + bf16 ----------------
__global__ __launch_bounds__(256) void add_ln(
    const u16* __restrict__ a, const float* __restrict__ res,
    const float* __restrict__ g, const float* __restrict__ be,
    float* __restrict__ outf, u16* __restrict__ outb)
{
    int row = blockIdx.x, tid = threadIdx.x;
    const u16* pa = a + (size_t)row * D_;
    const float* pr = res + (size_t)row * D_;
    float vals[4];
    float s = 0.0f;
    #pragma unroll
    for (int t = 0; t < 4; ++t) {
        float v = bf2f(pa[tid + t * 256]) + pr[tid + t * 256];
        vals[t] = v;
        s += v;
    }
    __shared__ float red[8];
    #pragma unroll
    for (int off = 32; off; off >>= 1) s += __shfl_xor(s, off);
    int wave = tid >> 6, lane = tid & 63;
    if (lane == 0) red[wave] = s;
    __syncthreads();
    float mean = (red[0] + red[1] + red[2] + red[3]) * (1.0f / D_);
    float vv = 0.0f;
    #pragma unroll
    for (int t = 0; t < 4; ++t) {
        float d = vals[t] - mean;
        vv += d * d;
    }
    #pragma unroll
    for (int off = 32; off; off >>= 1) vv += __shfl_xor(vv, off);
    if (lane == 0) red[4 + wave] = vv;
    __syncthreads();
    float var = (red[4] + red[5] + red[6] + red[7]) * (1.0f / D_);
    float rstd = rsqrtf(var + 1e-5f);
    #pragma unroll
    for (int t = 0; t < 4; ++t) {
        int c = tid + t * 256;
        float v = (vals[t] - mean) * rstd * g[c] + be[c];
        outf[(size_t)row * D_ + c] = v;
        outb[(size_t)row * D_ + c] = f2bf(v);
    }
}

// ---------------- user embedding gather (bf16) ----------------
__global__ __launch_bounds__(256) void gather_user(
    const float* __restrict__ ut, const int* __restrict__ ids, u16* __restrict__ out)
{
    int b = blockIdx.x;
    int uid = ids[b];
    for (int d = threadIdx.x; d < D_; d += 256)
        out[(size_t)b * D_ + d] = f2bf(ut[(size_t)uid * D_ + d]);
}

// ---------------- cross attention (q_len = 1), bf16 in/out ----------------
__global__ __launch_bounds__(64) void cross_attn(
    const u16* __restrict__ qh, const u16* __restrict__ kh, const u16* __restrict__ vh,
    u16* __restrict__ up)
{
    int bh = blockIdx.x;
    int b = bh >> 4, h = bh & 15;
    int lane = threadIdx.x;
    __shared__ float qv[DK_];
    qv[lane] = bf2f(qh[(size_t)b * D_ + h * DK_ + lane]);
    __syncthreads();
    float sc = -INFINITY;
    if (lane < S_) {
        float acc = 0.0f;
        const u16* krow = kh + ((size_t)(b * S_ + lane)) * D_ + h * DK_;
        #pragma unroll 8
        for (int d = 0; d < DK_; ++d) acc += qv[d] * bf2f(krow[d]);
        sc = acc * 0.125f;
    }
    float m = sc;
    #pragma unroll
    for (int off = 32; off; off >>= 1) m = fmaxf(m, __shfl_xor(m, off));
    float e = (lane < S_) ? expf(sc - m) : 0.0f;
    float sum = e;
    #pragma unroll
    for (int off = 32; off; off >>= 1) sum += __shfl_xor(sum, off);
    float aval = e / sum;
    float acc = 0.0f;
    for (int j = 0; j < S_; ++j) {
        float aj = __shfl(aval, j);
        acc += aj * bf2f(vh[((size_t)(b * S_ + j)) * D_ + h * DK_ + lane]);
    }
    up[(size_t)b * D_ + h * DK_ + lane] = f2bf(acc);
}

// ---------------- sequence mean (bf16 out) ----------------
__global__ __launch_bounds__(256) void seq_mean(const float* __restrict__ x, u16* __restrict__ out)
{
    int b = blockIdx.x;
    for (int d = threadIdx.x; d < D_; d += 256) {
        float s = 0.0f;
        for (int si = 0; si < S_; ++si)
            s += x[((size_t)(b * S_ + si)) * D_ + d];
        out[(size_t)b * D_ + d] = f2bf(s * (1.0f / S_));
    }
}

// ---------------- column copies ----------------
__global__ __launch_bounds__(256) void copy_cols(
    const float* __restrict__ src, float* __restrict__ dst,
    int width, int dstStride, int dstOff)
{
    int r = blockIdx.x;
    for (int c = threadIdx.x; c < width; c += 256)
        dst[(size_t)r * dstStride + dstOff + c] = src[(size_t)r * width + c];
}
__global__ __launch_bounds__(256) void copy_cols_b(
    const u16* __restrict__ src, u16* __restrict__ dst,
    int width, int dstStride, int dstOff)
{
    int r = blockIdx.x;
    for (int c = threadIdx.x; c < width; c += 256)
        dst[(size_t)r * dstStride + dstOff + c] = src[(size_t)r * width + c];
}

// ---------------- small fp32 GEMM (tiny-N heads) ----------------
__global__ __launch_bounds__(256) void gemm_bias_act(
    const float* __restrict__ A, const float* __restrict__ W,
    const float* __restrict__ bias, float* __restrict__ C,
    int M, int N, int K, int act)
{
    __shared__ float As[16][64];
    __shared__ float Bs[16][68];
    const int tid = threadIdx.x;
    const int rowBase = blockIdx.y * 64;
    const int colBase = blockIdx.x * 64;
    const int tx = tid & 15, ty = tid >> 4;
    const int arow = tid >> 2;
    const int ak4  = (tid & 3) << 2;
    const int brow = tid >> 4;
    const int bn4  = (tid & 15) << 2;

    float acc[4][4] = {};

    for (int kb = 0; kb < K; kb += 16) {
        float4 av = *reinterpret_cast<const float4*>(&A[(size_t)(rowBase + arow) * K + kb + ak4]);
        As[ak4 + 0][arow] = av.x;
        As[ak4 + 1][arow] = av.y;
        As[ak4 + 2][arow] = av.z;
        As[ak4 + 3][arow] = av.w;
        #pragma unroll
        for (int t = 0; t < 4; ++t) {
            int n = colBase + bn4 + t;
            Bs[brow][bn4 + t] = (n < N) ? W[(size_t)(kb + brow) * N + n] : 0.0f;
        }
        __syncthreads();
        #pragma unroll
        for (int kk = 0; kk < 16; ++kk) {
            float4 a4 = *reinterpret_cast<const float4*>(&As[kk][ty << 2]);
            float4 b4 = *reinterpret_cast<const float4*>(&Bs[kk][tx << 2]);
            float ar[4] = { a4.x, a4.y, a4.z, a4.w };
            float br[4] = { b4.x, b4.y, b4.z, b4.w };
            #pragma unroll
            for (int i = 0; i < 4; ++i)
                #pragma unroll
                for (int j = 0; j < 4; ++j)
                    acc[i][j] += ar[i] * br[j];
        }
        __syncthreads();
    }

    #pragma unroll
    for (int i = 0; i < 4; ++i) {
        int r = rowBase + (ty << 2) + i;
        #pragma unroll
        for (int j = 0; j < 4; ++j) {
            int c = colBase + (tx << 2) + j;
            if (c < N && r < M) {
                float v = acc[i][j] + (bias ? bias[c] : 0.0f);
                if (act == 1) v = gelu_exact(v);
                else if (act == 2) v = 1.0f / (1.0f + expf(-v));
                C[(size_t)r * N + c] = v;
            }
        }
    }
}

// ---------------- order softmax ----------------
__global__ __launch_bounds__(128) void order_softmax(const float* __restrict__ in, float* __restrict__ out)
{
    int b = threadIdx.x;
    if (b >= B_) return;
    float a = in[b * 2], c = in[b * 2 + 1];
    float m = fmaxf(a, c);
    float ea = expf(a - m), ec = expf(c - m);
    float s = ea + ec;
    out[b * 2] = ea / s;
    out[b * 2 + 1] = ec / s;
}

// ---------------- host-side launcher ----------------
extern "C" void kernel_launch(void* const* d_in, const int* in_sizes, int n_in,
                              void* d_out, int out_size, void* d_ws, size_t ws_size,
                              hipStream_t stream) {
    const float* movie_table = (const float*)d_in[0];
    const float* fran_table  = (const float*)d_in[1];
    const float* entry_table = (const float*)d_in[2];
    const float* proj_w      = (const float*)d_in[3];
    const float* proj_b      = (const float*)d_in[4];
    const float* wq          = (const float*)d_in[5];
    const float* bq          = (const float*)d_in[6];
    const float* wk          = (const float*)d_in[7];
    const float* bk          = (const float*)d_in[8];
    const float* wv          = (const float*)d_in[9];
    const float* bv          = (const float*)d_in[10];
    const float* wo          = (const float*)d_in[11];
    const float* bo          = (const float*)d_in[12];
    const float* rel_table   = (const float*)d_in[13];
    const float* aln_g       = (const float*)d_in[14];
    const float* aln_b       = (const float*)d_in[15];
    const float* f_w1        = (const float*)d_in[16];
    const float* f_b1        = (const float*)d_in[17];
    const float* f_w2        = (const float*)d_in[18];
    const float* f_b2        = (const float*)d_in[19];
    const float* ln_g        = (const float*)d_in[20];
    const float* ln_b        = (const float*)d_in[21];
    const float* user_table  = (const float*)d_in[22];
    const float* mq_w        = (const float*)d_in[23];
    const float* mq_b        = (const float*)d_in[24];
    const float* mk_w        = (const float*)d_in[25];
    const float* mk_b        = (const float*)d_in[26];
    const float* mv_w        = (const float*)d_in[27];
    const float* mv_b        = (const float*)d_in[28];
    const float* mo_w        = (const float*)d_in[29];
    const float* mo_b        = (const float*)d_in[30];
    const float* c_w1        = (const float*)d_in[31];
    const float* c_b1        = (const float*)d_in[32];
    const float* c_w2        = (const float*)d_in[33];
    const float* c_b2        = (const float*)d_in[34];
    const float* n_w1        = (const float*)d_in[35];
    const float* n_b1        = (const float*)d_in[36];
    const float* n_w2        = (const float*)d_in[37];
    const float* n_b2        = (const float*)d_in[38];
    const float* r_w1        = (const float*)d_in[39];
    const float* r_b1        = (const float*)d_in[40];
    const float* r_w2        = (const float*)d_in[41];
    const float* r_b2        = (const float*)d_in[42];
    const float* o_w1        = (const float*)d_in[43];
    const float* o_b1        = (const float*)d_in[44];
    const float* o_w2        = (const float*)d_in[45];
    const float* o_b2        = (const float*)d_in[46];
    const int* user_ids      = (const int*)d_in[47];
    const int* movie_ids     = (const int*)d_in[48];
    const int* franchise_ids = (const int*)d_in[49];
    const int* entry_types   = (const int*)d_in[50];
    const int* relation_mat  = (const int*)d_in[51];

    // ---- workspace layout ----
    u16* up16 = (u16*)d_ws;
    u16* proj_wt = up16;                                   // [1024][1536]
    u16* wqkv_t  = proj_wt + (size_t)1024 * 1536;          // [4][3072][1024]
    u16* wo_t    = wqkv_t  + (size_t)4 * 3072 * 1024;      // [4][1024][1024]
    u16* fw1_buf = wo_t    + (size_t)4 * 1024 * 1024;      // [4096][1024] (per-layer)
    u16* fw2_buf = fw1_buf + (size_t)4096 * 1024;          // [1024][4096] (per-layer)
    u16* mq_t    = fw2_buf + (size_t)1024 * 4096;          // [1024][1024]
    u16* mk_t    = mq_t    + (size_t)1024 * 1024;
    u16* mv_t    = mk_t    + (size_t)1024 * 1024;
    u16* mo_t    = mv_t    + (size_t)1024 * 1024;
    u16* c_w1t   = mo_t    + (size_t)1024 * 1024;          // [1024][2048]
    u16* n_w1t   = c_w1t   + (size_t)1024 * 2048;          // [1024][2048]
    u16* r_w1t   = n_w1t   + (size_t)1024 * 2048;          // [1024][3072]
    u16* o_w1t   = r_w1t   + (size_t)1024 * 3072;          // [512][1024]
    u16* ffb     = o_w1t   + (size_t)512 * 1024;           // [6400][4096]  (union with xinb)
    u16* xinb    = ffb;                                    // [6400][1536]  (dead after proj)
    u16* xb      = ffb     + (size_t)BS_ * FF_;            // [6400][1024]
    u16* qkvb    = xb      + (size_t)BS_ * D_;             // [6400][3072]
    u16* ctxb    = qkvb    + (size_t)BS_ * 3 * D_;         // [6400][1024]
    u16* ob      = ctxb    + (size_t)BS_ * D_;             // [6400][1024]
    u16* ueb     = ob      + (size_t)BS_ * D_;             // [128][1024]
    u16* upb_pre = ueb     + (size_t)B_ * D_;              // [128][1024]
    u16* upb     = upb_pre + (size_t)B_ * D_;              // [128][1024]
    u16* seqb    = upb     + (size_t)B_ * D_;              // [128][1024]
    u16* cib     = seqb    + (size_t)B_ * D_;              // [128][2048]
    u16* rib     = cib     + (size_t)B_ * 2 * D_;          // [128][3072]
    float* fp    = (float*)(rib + (size_t)B_ * 3 * D_);
    float* bqkv  = fp;                                     // [4][3072]
    float* pet   = bqkv + 4 * 3072;                        // [50][1024]
    float* h1    = pet  + 50 * 1024;                       // [128][1024]
    float* ho    = h1   + (size_t)B_ * D_;                 // [128][512]

    // ---- d_out layout ----
    float* xout    = (float*)d_out;                 // [BS, D]
    float* comp    = xout + (size_t)BS_ * D_;       // [B,1]
    float* logits  = comp + B_;                     // [B,V]
    float* rating  = logits + (size_t)B_ * V_;      // [B,1]
    float* order   = rating + B_;                   // [B,2]
    float* upref   = order + 2 * B_;                // [B,D]

    dim3 blk(256);

    // ---- weight conversion pass ----
    wtrans<<<dim3(32, 48, 1), blk, 0, stream>>>(proj_w, proj_wt, 1536, 1024, 0, 0, 0);
    wtrans<<<dim3(32, 32, 4), blk, 0, stream>>>(wq, wqkv_t, 1024, 1024, 1048576, 3145728, 0);
    wtrans<<<dim3(32, 32, 4), blk, 0, stream>>>(wk, wqkv_t, 1024, 1024, 1048576, 3145728, 1024);
    wtrans<<<dim3(32, 32, 4), blk, 0, stream>>>(wv, wqkv_t, 1024, 1024, 1048576, 3145728, 2048);
    wtrans<<<dim3(32, 32, 4), blk, 0, stream>>>(wo, wo_t, 1024, 1024, 1048576, 1048576, 0);
    wtrans<<<dim3(32, 32, 1), blk, 0, stream>>>(mq_w, mq_t, 1024, 1024, 0, 0, 0);
    wtrans<<<dim3(32, 32, 1), blk, 0, stream>>>(mk_w, mk_t, 1024, 1024, 0, 0, 0);
    wtrans<<<dim3(32, 32, 1), blk, 0, stream>>>(mv_w, mv_t, 1024, 1024, 0, 0, 0);
    wtrans<<<dim3(32, 32, 1), blk, 0, stream>>>(mo_w, mo_t, 1024, 1024, 0, 0, 0);
    wtrans<<<dim3(32, 64, 1), blk, 0, stream>>>(c_w1, c_w1t, 2048, 1024, 0, 0, 0);
    wtrans<<<dim3(32, 64, 1), blk, 0, stream>>>(n_w1, n_w1t, 2048, 1024, 0, 0, 0);
    wtrans<<<dim3(32, 96, 1), blk, 0, stream>>>(r_w1, r_w1t, 3072, 1024, 0, 0, 0);
    wtrans<<<dim3(16, 32, 1), blk, 0, stream>>>(o_w1, o_w1t, 1024, 512, 0, 0, 0);
    copy_cols<<<4, blk, 0, stream>>>(bq, bqkv, 1024, 3072, 0);
    copy_cols<<<4, blk, 0, stream>>>(bk, bqkv, 1024, 3072, 1024);
    copy_cols<<<4, blk, 0, stream>>>(bv, bqkv, 1024, 3072, 2048);
    pe_table<<<S_, blk, 0, stream>>>(pet);

    // ---- encoder input ----
    embed_concat<<<BS_, blk, 0, stream>>>(movie_table, fran_table, entry_table,
                                          movie_ids, franchise_ids, entry_types, xinb);
    gemm_bf16<<<dim3(8, 50), blk, 0, stream>>>(xinb, proj_wt, proj_b, xout, nullptr,
                                               BS_, D_, 3 * E_, 0);
    pe_apply<<<BS_, blk, 0, stream>>>(xout, pet, xb);

    // ---- transformer layers ----
    for (int l = 0; l < L_; ++l) {
        gemm_bf16<<<dim3(24, 50), blk, 0, stream>>>(xb, wqkv_t + (size_t)l * 3145728,
                                                    bqkv + l * 3072, nullptr, qkvb,
                                                    BS_, 3 * D_, D_, 0);
        attn_kernel<<<B_ * H_, blk, 0, stream>>>(qkvb, rel_table + (size_t)l * 5 * DK_,
                                                 relation_mat, ctxb);
        gemm_bf16<<<dim3(8, 50), blk, 0, stream>>>(ctxb, wo_t + (size_t)l * 1048576,
                                                   bo + l * D_, nullptr, ob,
                                                   BS_, D_, D_, 0);
        add_ln<<<BS_, blk, 0, stream>>>(ob, xout, aln_g + l * D_, aln_b + l * D_, xout, xb);
        wtrans<<<dim3(128, 32, 1), blk, 0, stream>>>(f_w1 + (size_t)l * D_ * FF_, fw1_buf,
                                                     1024, 4096, 0, 0, 0);
        gemm_bf16<<<dim3(32, 50), blk, 0, stream>>>(xb, fw1_buf, f_b1 + l * FF_,
                                                    nullptr, ffb, BS_, FF_, D_, 1);
        wtrans<<<dim3(32, 128, 1), blk, 0, stream>>>(f_w2 + (size_t)l * FF_ * D_, fw2_buf,
                                                     4096, 1024, 0, 0, 0);
        gemm_bf16<<<dim3(8, 50), blk, 0, stream>>>(ffb, fw2_buf, f_b2 + l * D_,
                                                   nullptr, ob, BS_, D_, FF_, 0);
        add_ln<<<BS_, blk, 0, stream>>>(ob, xout, ln_g + l * D_, ln_b + l * D_, xout, xb);
    }

    // ---- user cross-attention ----
    gather_user<<<B_, blk, 0, stream>>>(user_table, user_ids, ueb);
    gemm_bf16<<<dim3(8, 1), blk, 0, stream>>>(ueb, mq_t, mq_b, nullptr, qkvb, B_, D_, D_, 0);
    gemm_bf16<<<dim3(8, 50), blk, 0, stream>>>(xb, mk_t, mk_b, nullptr, ctxb, BS_, D_, D_, 0);
    gemm_bf16<<<dim3(8, 50), blk, 0, stream>>>(xb, mv_t, mv_b, nullptr, ob, BS_, D_, D_, 0);
    cross_attn<<<B_ * H_, dim3(64), 0, stream>>>(qkvb, ctxb, ob, upb_pre);
    gemm_bf16<<<dim3(8, 1), blk, 0, stream>>>(upb_pre, mo_t, mo_b, upref, upb, B_, D_, D_, 0);

    // ---- sequence mean + concats ----
    seq_mean<<<B_, blk, 0, stream>>>(xout, seqb);
    copy_cols_b<<<B_, blk, 0, stream>>>(upb,  cib, D_, 2 * D_, 0);
    copy_cols_b<<<B_, blk, 0, stream>>>(seqb, cib, D_, 2 * D_, D_);
    copy_cols_b<<<B_, blk, 0, stream>>>(ueb,  rib, D_, 3 * D_, 0);
    copy_cols_b<<<B_, blk, 0, stream>>>(upb,  rib, D_, 3 * D_, D_);
    copy_cols_b<<<B_, blk, 0, stream>>>(seqb, rib, D_, 3 * D_, 2 * D_);

    // ---- heads ----
    gemm_bf16<<<dim3(8, 1), blk, 0, stream>>>(cib, c_w1t, c_b1, h1, nullptr, B_, D_, 2 * D_, 1);
    gemm_bias_act<<<dim3(1, 2), blk, 0, stream>>>(h1, c_w2, c_b2, comp, B_, 1, D_, 2);
    gemm_bf16<<<dim3(8, 1), blk, 0, stream>>>(cib, n_w1t, n_b1, h1, nullptr, B_, D_, 2 * D_, 1);
    gemm_mfma<<<dim3(782, 1), blk, 0, stream>>>(h1, n_w2, n_b2, logits, B_, V_, D_, 0);
    gemm_bf16<<<dim3(8, 1), blk, 0, stream>>>(rib, r_w1t, r_b1, h1, nullptr, B_, D_, 3 * D_, 1);
    gemm_bias_act<<<dim3(1, 2), blk, 0, stream>>>(h1, r_w2, r_b2, rating, B_, 1, D_, 0);
    gemm_bf16<<<dim3(4, 1), blk, 0, stream>>>(upb, o_w1t, o_b1, ho, nullptr, B_, 512, D_, 1);
    gemm_bias_act<<<dim3(1, 2), blk, 0, stream>>>(ho, o_w2, o_b2, h1, B_, 2, 512, 0);
    order_softmax<<<1, dim3(128), 0, stream>>>(h1, order);
}

// Round 5
// 2651.723 us; speedup vs baseline: 4.6740x; 1.0794x over previous
//
#include <hip/hip_runtime.h>
#include <hip/hip_bf16.h>
#include <math.h>

// ---------------- problem constants ----------------
#define B_   128
#define S_   50
#define BS_  (B_*S_)        // 6400
#define E_   512
#define D_   1024
#define H_   16
#define DK_  64
#define L_   4
#define FF_  4096
#define V_   100000

typedef short bf8_t __attribute__((ext_vector_type(8)));
typedef float f32x4 __attribute__((ext_vector_type(4)));
typedef unsigned short u16;

__device__ __forceinline__ float gelu_exact(float x) {
    return 0.5f * x * (1.0f + erff(x * 0.70710678118654752440f));
}
// fp32 -> bf16 bits, round-to-nearest-even
__device__ __forceinline__ u16 f2bf(float f) {
    unsigned int u = __float_as_uint(f);
    return (u16)((u + 0x7FFFu + ((u >> 16) & 1u)) >> 16);
}
__device__ __forceinline__ float bf2f(u16 u) {
    return __uint_as_float(((unsigned int)u) << 16);
}

// async global->LDS, 16B per lane (dest is wave-uniform base + lane*16)
__device__ __forceinline__ void gload16(const u16* g, u16* l) {
    auto* g1 = reinterpret_cast<const __attribute__((address_space(1))) unsigned int*>(
                   reinterpret_cast<uintptr_t>(g));
    auto* l3 = reinterpret_cast<__attribute__((address_space(3))) unsigned int*>(
                   reinterpret_cast<uintptr_t>(l));
    __builtin_amdgcn_global_load_lds(g1, l3, 16, 0, 0);
}

// ---------------- weight convert+transpose: Wt[n][k] = bf16(W[k][n]) ----------------
__global__ __launch_bounds__(256) void wtrans(
    const float* __restrict__ W, u16* __restrict__ Wt,
    int K, int N, long srcLS, long dstLS, int dstRowOff)
{
    __shared__ float t[32][33];
    int nb = blockIdx.x * 32, kb = blockIdx.y * 32, l = blockIdx.z;
    W  += (size_t)l * srcLS;
    Wt += (size_t)l * dstLS;
    int c = threadIdx.x & 31, r0 = threadIdx.x >> 5;  // r0 in 0..7
    #pragma unroll
    for (int rr = 0; rr < 32; rr += 8)
        t[rr + r0][c] = W[(size_t)(kb + rr + r0) * N + nb + c];
    __syncthreads();
    #pragma unroll
    for (int rr = 0; rr < 32; rr += 8)
        Wt[(size_t)(dstRowOff + nb + rr + r0) * K + kb + c] = f2bf(t[c][rr + r0]);
}

// ---------------- embedding gather + concat (bf16 out) ----------------
__global__ __launch_bounds__(256) void embed_concat(
    const float* __restrict__ mt, const float* __restrict__ ft, const float* __restrict__ et,
    const int* __restrict__ mids, const int* __restrict__ fids, const int* __restrict__ eids,
    u16* __restrict__ xinb)
{
    int bs = blockIdx.x;
    int mid = mids[bs], fid = fids[bs], eid = eids[bs];
    const float* srcs[3] = { mt + (size_t)mid * E_, ft + (size_t)fid * E_, et + (size_t)eid * E_ };
    u16* dst = xinb + (size_t)bs * (3 * E_);
    for (int i = threadIdx.x; i < 384; i += 256) {       // 384 float4 = 1536 floats
        int seg = i >> 7, off = i & 127;
        float4 v = reinterpret_cast<const float4*>(srcs[seg])[off];
        ushort4 b;
        b.x = f2bf(v.x); b.y = f2bf(v.y); b.z = f2bf(v.z); b.w = f2bf(v.w);
        reinterpret_cast<ushort4*>(dst + seg * E_)[off] = b;
    }
}

// ---------------- positional encoding table [50][1024] ----------------
__global__ __launch_bounds__(256) void pe_table(float* __restrict__ pet)
{
    int s = blockIdx.x;
    const float c = -logf(10000.0f) / 512.0f;
    for (int d = threadIdx.x; d < D_; d += 256) {
        int second = d >= 512;
        int cc = second ? d - 512 : d;
        int i = cc >> 1;
        float div = expf(c * (float)(2 * i));
        float a = (float)s * div * (second ? 1.5f : 1.0f);
        pet[s * D_ + d] = (cc & 1) ? cosf(a) : sinf(a);
    }
}

// ---------------- bf16 MFMA GEMM v2: 2-phase dbuf + swizzled LDS ----------------
// A bf16 [M,K] row-major, Wt bf16 [N,K] row-major, bias fp32[N].
// M%128==0, N%128==0, K%32==0. Cf (fp32) / Cb (bf16) outputs; optional PE add.
// LDS layout: [row][chunk] holds global[row][chunk ^ (row&3)], chunk = 8 u16 (16B).
__global__ __launch_bounds__(256) void gemm_bf16(
    const u16* __restrict__ A, const u16* __restrict__ Wt,
    const float* __restrict__ bias, float* __restrict__ Cf, u16* __restrict__ Cb,
    int M, int N, int K, int act, const float* __restrict__ pe)
{
    __shared__ u16 As[2 * 128 * 32];
    __shared__ u16 Bs[2 * 128 * 32];
    const int tid  = threadIdx.x;
    const int lane = tid & 63;
    const int wid  = tid >> 6;
    const int wr   = wid >> 1, wc = wid & 1;
    const int rowBase = blockIdx.y * 128;
    const int colBase = blockIdx.x * 128;
    const int fr = lane & 15;

    // ---- staging geometry (per-wave: rows [wid*32, wid*32+32), two gloads) ----
    const int sRowL  = lane >> 2;          // 0..15 within one gload
    const int sChunk = lane & 3;           // 16B chunk within 64B row
    const int gRow0  = (wid << 5) + sRowL; // tile row of first gload
    const int gRow1  = gRow0 + 16;
    const int gC0 = sChunk ^ (gRow0 & 3);  // inverse-swizzled global chunk
    const int gC1 = sChunk ^ (gRow1 & 3);
    const u16* aS0 = A  + (size_t)(rowBase + gRow0) * K + (gC0 << 3);
    const u16* aS1 = A  + (size_t)(rowBase + gRow1) * K + (gC1 << 3);
    const u16* bS0 = Wt + (size_t)(colBase + gRow0) * K + (gC0 << 3);
    const u16* bS1 = Wt + (size_t)(colBase + gRow1) * K + (gC1 << 3);
    const int ldsOff0 = (wid << 5) << 5;   // wid*32 rows * 32 elems
    const int ldsOff1 = ldsOff0 + (16 << 5);

    // ---- MFMA fragment read addresses (swizzled) ----
    const int swzOff = (((lane >> 4) ^ (fr & 3)) << 3);   // element offset in row
    const int aRd = (wr * 64 + fr) * 32 + swzOff;         // + m*512
    const int bRd = (wc * 64 + fr) * 32 + swzOff;         // + n*512

    u16* cA = As;            u16* cB = Bs;
    u16* nA = As + 128 * 32; u16* nB = Bs + 128 * 32;

    f32x4 acc[4][4] = {};
    const int nk = K >> 5;

    // prologue: stage tile 0
    gload16(aS0, cA + ldsOff0);
    gload16(aS1, cA + ldsOff1);
    gload16(bS0, cB + ldsOff0);
    gload16(bS1, cB + ldsOff1);
    __syncthreads();

    for (int t = 0; t < nk; ++t) {
        if (t + 1 < nk) {
            const int kb = (t + 1) << 5;
            gload16(aS0 + kb, nA + ldsOff0);
            gload16(aS1 + kb, nA + ldsOff1);
            gload16(bS0 + kb, nB + ldsOff0);
            gload16(bS1 + kb, nB + ldsOff1);
        }
        bf8_t af[4], bf[4];
        #pragma unroll
        for (int m = 0; m < 4; ++m)
            af[m] = *reinterpret_cast<const bf8_t*>(&cA[aRd + m * 512]);
        #pragma unroll
        for (int n = 0; n < 4; ++n)
            bf[n] = *reinterpret_cast<const bf8_t*>(&cB[bRd + n * 512]);
        #pragma unroll
        for (int m = 0; m < 4; ++m)
            #pragma unroll
            for (int n = 0; n < 4; ++n)
                acc[m][n] = __builtin_amdgcn_mfma_f32_16x16x32_bf16(af[m], bf[n], acc[m][n], 0, 0, 0);
        __syncthreads();   // drains vmcnt (next tile landed) + lgkm, then barrier
        u16* tp;
        tp = cA; cA = nA; nA = tp;
        tp = cB; cB = nB; nB = tp;
    }

    // epilogue: C/D map col=lane&15, row=(lane>>4)*4+reg
    const int orow = (lane >> 4) << 2;
    #pragma unroll
    for (int m = 0; m < 4; ++m) {
        int r0 = rowBase + wr * 64 + m * 16 + orow;
        #pragma unroll
        for (int n = 0; n < 4; ++n) {
            int c = colBase + wc * 64 + n * 16 + fr;
            float bv = bias ? bias[c] : 0.0f;
            #pragma unroll
            for (int r = 0; r < 4; ++r) {
                float v = acc[m][n][r] + bv;
                if (act == 1) v = gelu_exact(v);
                if (pe) v += pe[(size_t)((r0 + r) % S_) * N + c];
                if (Cf) Cf[(size_t)(r0 + r) * N + c] = v;
                if (Cb) Cb[(size_t)(r0 + r) * N + c] = f2bf(v);
            }
        }
    }
}

// ---------------- fp32-input MFMA GEMM (logits: W streamed fp32) ----------------
__global__ __launch_bounds__(256) void gemm_mfma(
    const float* __restrict__ A, const float* __restrict__ W,
    const float* __restrict__ bias, float* __restrict__ C,
    int M, int N, int K, int act)
{
    __shared__ u16 As[128][40];
    __shared__ u16 Bs[128][40];
    const int tid  = threadIdx.x;
    const int lane = tid & 63;
    const int wid  = tid >> 6;
    const int wr   = wid >> 1, wc = wid & 1;
    const int rowBase = blockIdx.y * 128;
    const int colBase = blockIdx.x * 128;

    const int a_r = tid >> 1;
    const int a_h = (tid & 1) << 4;
    const int b_c = tid & 127;
    const int b_h = (tid >> 7) << 4;

    const int fr = lane & 15;
    const int fk = (lane >> 4) << 3;

    f32x4 acc[4][4] = {};
    const int nvalid = N - colBase;

    for (int kb = 0; kb < K; kb += 32) {
        const float* Ap = A + (size_t)(rowBase + a_r) * K + kb + a_h;
        #pragma unroll
        for (int q = 0; q < 4; ++q) {
            float4 v = *reinterpret_cast<const float4*>(Ap + q * 4);
            ushort4 bb;
            bb.x = f2bf(v.x); bb.y = f2bf(v.y); bb.z = f2bf(v.z); bb.w = f2bf(v.w);
            *reinterpret_cast<ushort4*>(&As[a_r][a_h + q * 4]) = bb;
        }
        {
            u16 tmp[16];
            const float* Wp = W + (size_t)(kb + b_h) * N + colBase + b_c;
            bool valid = (b_c < nvalid);
            #pragma unroll
            for (int kk2 = 0; kk2 < 16; ++kk2) {
                float v = valid ? Wp[(size_t)kk2 * N] : 0.0f;
                tmp[kk2] = f2bf(v);
            }
            #pragma unroll
            for (int h2 = 0; h2 < 2; ++h2)
                *reinterpret_cast<bf8_t*>(&Bs[b_c][b_h + h2 * 8]) =
                    *reinterpret_cast<const bf8_t*>(&tmp[h2 * 8]);
        }
        __syncthreads();

        bf8_t af[4], bfv[4];
        #pragma unroll
        for (int m = 0; m < 4; ++m)
            af[m] = *reinterpret_cast<const bf8_t*>(&As[wr * 64 + m * 16 + fr][fk]);
        #pragma unroll
        for (int n = 0; n < 4; ++n)
            bfv[n] = *reinterpret_cast<const bf8_t*>(&Bs[wc * 64 + n * 16 + fr][fk]);
        #pragma unroll
        for (int m = 0; m < 4; ++m)
            #pragma unroll
            for (int n = 0; n < 4; ++n)
                acc[m][n] = __builtin_amdgcn_mfma_f32_16x16x32_bf16(af[m], bfv[n], acc[m][n], 0, 0, 0);
        __syncthreads();
    }

    const int orow = (lane >> 4) << 2;
    #pragma unroll
    for (int m = 0; m < 4; ++m) {
        int r0 = rowBase + wr * 64 + m * 16 + orow;
        #pragma unroll
        for (int n = 0; n < 4; ++n) {
            int c = colBase + wc * 64 + n * 16 + fr;
            if (c < N) {
                float bv = bias ? bias[c] : 0.0f;
                #pragma unroll
                for (int r = 0; r < 4; ++r) {
                    float v = acc[m][n][r] + bv;
                    if (act == 1) v = gelu_exact(v);
                    else if (act == 2) v = 1.0f / (1.0f + expf(-v));
                    C[(size_t)(r0 + r) * N + c] = v;
                }
            }
        }
    }
}

// ---------------- self-attention (per (b,h) block), bf16 qkv merged [BS,3072] ----------------
// R-table trick: q.rel[i,j,:] = R[i, rm[i,j]], R = q @ rel_table^T (5 rel types)
__global__ __launch_bounds__(256) void attn_kernel(
    const u16* __restrict__ qkv, const float* __restrict__ rt, const int* __restrict__ rm,
    u16* __restrict__ ctxb)
{
    int bh = blockIdx.x;
    int b = bh >> 4, h = bh & 15;
    __shared__ float qs[S_][DK_ + 1], ks[S_][DK_ + 1], vs[S_][DK_ + 1];
    __shared__ float rts[5][DK_];
    __shared__ float Rs[S_][8];
    int tid = threadIdx.x;
    int wave = tid >> 6, lane = tid & 63;

    for (int idx = tid; idx < S_ * DK_; idx += 256) {
        int s = idx >> 6, d = idx & 63;
        size_t g = ((size_t)(b * S_ + s)) * (3 * D_) + h * DK_ + d;
        qs[s][d] = bf2f(qkv[g]);
        ks[s][d] = bf2f(qkv[g + D_]);
        vs[s][d] = bf2f(qkv[g + 2 * D_]);
    }
    for (int i = tid; i < 5 * DK_; i += 256)
        rts[i >> 6][i & 63] = rt[i];
    __syncthreads();

    for (int t = tid; t < S_ * 5; t += 256) {
        int i = t / 5, r = t - 5 * i;
        float a = 0.0f;
        #pragma unroll 8
        for (int d = 0; d < DK_; ++d) a += qs[i][d] * rts[r][d];
        Rs[i][r] = a;
    }
    __syncthreads();

    const float scale = 0.125f;
    for (int i = wave; i < S_; i += 4) {
        float sc = -INFINITY;
        if (lane < S_) {
            float acc = 0.0f;
            #pragma unroll 8
            for (int d = 0; d < DK_; ++d) acc += qs[i][d] * ks[lane][d];
            sc = acc * scale + 0.5f * Rs[i][rm[i * S_ + lane]];
        }
        float m = sc;
        #pragma unroll
        for (int off = 32; off; off >>= 1) m = fmaxf(m, __shfl_xor(m, off));
        float e = (lane < S_) ? expf(sc - m) : 0.0f;
        float sum = e;
        #pragma unroll
        for (int off = 32; off; off >>= 1) sum += __shfl_xor(sum, off);
        float aval = e / sum;

        float acc = 0.0f;
        for (int j = 0; j < S_; ++j) {
            float aj = __shfl(aval, j);
            acc += aj * vs[j][lane];
        }
        ctxb[((size_t)(b * S_ + i)) * D_ + h * DK_ + lane] = f2bf(acc);
    }
}

// ---------------- add + layernorm: out = LN(bf16(a) + res); writes fp32 + bf16 ----------------
__global__ __launch_bounds__(256) void add_ln(
    const u16* __restrict__ a, const float* __restrict__ res,
    const float* __restrict__ g, const float* __restrict__ be,
    float* __restrict__ outf, u16* __restrict__ outb)
{
    int row = blockIdx.x, tid = threadIdx.x;
    const u16* pa = a + (size_t)row * D_;
    const float* pr = res + (size_t)row * D_;
    float vals[4];
    float s = 0.0f;
    #pragma unroll
    for (int t = 0; t < 4; ++t) {
        float v = bf2f(pa[tid + t * 256]) + pr[tid + t * 256];
        vals[t] = v;
        s += v;
    }
    __shared__ float red[8];
    #pragma unroll
    for (int off = 32; off; off >>= 1) s += __shfl_xor(s, off);
    int wave = tid >> 6, lane = tid & 63;
    if (lane == 0) red[wave] = s;
    __syncthreads();
    float mean = (red[0] + red[1] + red[2] + red[3]) * (1.0f / D_);
    float vv = 0.0f;
    #pragma unroll
    for (int t = 0; t < 4; ++t) {
        float d = vals[t] - mean;
        vv += d * d;
    }
    #pragma unroll
    for (int off = 32; off; off >>= 1) vv += __shfl_xor(vv, off);
    if (lane == 0) red[4 + wave] = vv;
    __syncthreads();
    float var = (red[4] + red[5] + red[6] + red[7]) * (1.0f / D_);
    float rstd = rsqrtf(var + 1e-5f);
    #pragma unroll
    for (int t = 0; t < 4; ++t) {
        int c = tid + t * 256;
        float v = (vals[t] - mean) * rstd * g[c] + be[c];
        outf[(size_t)row * D_ + c] = v;
        outb[(size_t)row * D_ + c] = f2bf(v);
    }
}

// ---------------- user embedding gather (bf16) ----------------
__global__ __launch_bounds__(256) void gather_user(
    const float* __restrict__ ut, const int* __restrict__ ids, u16* __restrict__ out)
{
    int b = blockIdx.x;
    int uid = ids[b];
    for (int d = threadIdx.x; d < D_; d += 256)
        out[(size_t)b * D_ + d] = f2bf(ut[(size_t)uid * D_ + d]);
}

// ---------------- cross attention (q_len = 1), bf16 in/out ----------------
__global__ __launch_bounds__(64) void cross_attn(
    const u16* __restrict__ qh, const u16* __restrict__ kh, const u16* __restrict__ vh,
    u16* __restrict__ up)
{
    int bh = blockIdx.x;
    int b = bh >> 4, h = bh & 15;
    int lane = threadIdx.x;
    __shared__ float qv[DK_];
    qv[lane] = bf2f(qh[(size_t)b * D_ + h * DK_ + lane]);
    __syncthreads();
    float sc = -INFINITY;
    if (lane < S_) {
        float acc = 0.0f;
        const u16* krow = kh + ((size_t)(b * S_ + lane)) * D_ + h * DK_;
        #pragma unroll 8
        for (int d = 0; d < DK_; ++d) acc += qv[d] * bf2f(krow[d]);
        sc = acc * 0.125f;
    }
    float m = sc;
    #pragma unroll
    for (int off = 32; off; off >>= 1) m = fmaxf(m, __shfl_xor(m, off));
    float e = (lane < S_) ? expf(sc - m) : 0.0f;
    float sum = e;
    #pragma unroll
    for (int off = 32; off; off >>= 1) sum += __shfl_xor(sum, off);
    float aval = e / sum;
    float acc = 0.0f;
    for (int j = 0; j < S_; ++j) {
        float aj = __shfl(aval, j);
        acc += aj * bf2f(vh[((size_t)(b * S_ + j)) * D_ + h * DK_ + lane]);
    }
    up[(size_t)b * D_ + h * DK_ + lane] = f2bf(acc);
}

// ---------------- sequence mean (bf16 out) ----------------
__global__ __launch_bounds__(256) void seq_mean(const float* __restrict__ x, u16* __restrict__ out)
{
    int b = blockIdx.x;
    for (int d = threadIdx.x; d < D_; d += 256) {
        float s = 0.0f;
        for (int si = 0; si < S_; ++si)
            s += x[((size_t)(b * S_ + si)) * D_ + d];
        out[(size_t)b * D_ + d] = f2bf(s * (1.0f / S_));
    }
}

// ---------------- column copies ----------------
__global__ __launch_bounds__(256) void copy_cols(
    const float* __restrict__ src, float* __restrict__ dst,
    int width, int dstStride, int dstOff)
{
    int r = blockIdx.x;
    for (int c = threadIdx.x; c < width; c += 256)
        dst[(size_t)r * dstStride + dstOff + c] = src[(size_t)r * width + c];
}
__global__ __launch_bounds__(256) void copy_cols_b(
    const u16* __restrict__ src, u16* __restrict__ dst,
    int width, int dstStride, int dstOff)
{
    int r = blockIdx.x;
    for (int c = threadIdx.x; c < width; c += 256)
        dst[(size_t)r * dstStride + dstOff + c] = src[(size_t)r * width + c];
}

// ---------------- small fp32 GEMM (tiny-N heads) ----------------
__global__ __launch_bounds__(256) void gemm_bias_act(
    const float* __restrict__ A, const float* __restrict__ W,
    const float* __restrict__ bias, float* __restrict__ C,
    int M, int N, int K, int act)
{
    __shared__ float As[16][64];
    __shared__ float Bs[16][68];
    const int tid = threadIdx.x;
    const int rowBase = blockIdx.y * 64;
    const int colBase = blockIdx.x * 64;
    const int tx = tid & 15, ty = tid >> 4;
    const int arow = tid >> 2;
    const int ak4  = (tid & 3) << 2;
    const int brow = tid >> 4;
    const int bn4  = (tid & 15) << 2;

    float acc[4][4] = {};

    for (int kb = 0; kb < K; kb += 16) {
        float4 av = *reinterpret_cast<const float4*>(&A[(size_t)(rowBase + arow) * K + kb + ak4]);
        As[ak4 + 0][arow] = av.x;
        As[ak4 + 1][arow] = av.y;
        As[ak4 + 2][arow] = av.z;
        As[ak4 + 3][arow] = av.w;
        #pragma unroll
        for (int t = 0; t < 4; ++t) {
            int n = colBase + bn4 + t;
            Bs[brow][bn4 + t] = (n < N) ? W[(size_t)(kb + brow) * N + n] : 0.0f;
        }
        __syncthreads();
        #pragma unroll
        for (int kk = 0; kk < 16; ++kk) {
            float4 a4 = *reinterpret_cast<const float4*>(&As[kk][ty << 2]);
            float4 b4 = *reinterpret_cast<const float4*>(&Bs[kk][tx << 2]);
            float ar[4] = { a4.x, a4.y, a4.z, a4.w };
            float br[4] = { b4.x, b4.y, b4.z, b4.w };
            #pragma unroll
            for (int i = 0; i < 4; ++i)
                #pragma unroll
                for (int j = 0; j < 4; ++j)
                    acc[i][j] += ar[i] * br[j];
        }
        __syncthreads();
    }

    #pragma unroll
    for (int i = 0; i < 4; ++i) {
        int r = rowBase + (ty << 2) + i;
        #pragma unroll
        for (int j = 0; j < 4; ++j) {
            int c = colBase + (tx << 2) + j;
            if (c < N && r < M) {
                float v = acc[i][j] + (bias ? bias[c] : 0.0f);
                if (act == 1) v = gelu_exact(v);
                else if (act == 2) v = 1.0f / (1.0f + expf(-v));
                C[(size_t)r * N + c] = v;
            }
        }
    }
}

// ---------------- order softmax ----------------
__global__ __launch_bounds__(128) void order_softmax(const float* __restrict__ in, float* __restrict__ out)
{
    int b = threadIdx.x;
    if (b >= B_) return;
    float a = in[b * 2], c = in[b * 2 + 1];
    float m = fmaxf(a, c);
    float ea = expf(a - m), ec = expf(c - m);
    float s = ea + ec;
    out[b * 2] = ea / s;
    out[b * 2 + 1] = ec / s;
}

// ---------------- host-side launcher ----------------
extern "C" void kernel_launch(void* const* d_in, const int* in_sizes, int n_in,
                              void* d_out, int out_size, void* d_ws, size_t ws_size,
                              hipStream_t stream) {
    const float* movie_table = (const float*)d_in[0];
    const float* fran_table  = (const float*)d_in[1];
    const float* entry_table = (const float*)d_in[2];
    const float* proj_w      = (const float*)d_in[3];
    const float* proj_b      = (const float*)d_in[4];
    const float* wq          = (const float*)d_in[5];
    const float* bq          = (const float*)d_in[6];
    const float* wk          = (const float*)d_in[7];
    const float* bk          = (const float*)d_in[8];
    const float* wv          = (const float*)d_in[9];
    const float* bv          = (const float*)d_in[10];
    const float* wo          = (const float*)d_in[11];
    const float* bo          = (const float*)d_in[12];
    const float* rel_table   = (const float*)d_in[13];
    const float* aln_g       = (const float*)d_in[14];
    const float* aln_b       = (const float*)d_in[15];
    const float* f_w1        = (const float*)d_in[16];
    const float* f_b1        = (const float*)d_in[17];
    const float* f_w2        = (const float*)d_in[18];
    const float* f_b2        = (const float*)d_in[19];
    const float* ln_g        = (const float*)d_in[20];
    const float* ln_b        = (const float*)d_in[21];
    const float* user_table  = (const float*)d_in[22];
    const float* mq_w        = (const float*)d_in[23];
    const float* mq_b        = (const float*)d_in[24];
    const float* mk_w        = (const float*)d_in[25];
    const float* mk_b        = (const float*)d_in[26];
    const float* mv_w        = (const float*)d_in[27];
    const float* mv_b        = (const float*)d_in[28];
    const float* mo_w        = (const float*)d_in[29];
    const float* mo_b        = (const float*)d_in[30];
    const float* c_w1        = (const float*)d_in[31];
    const float* c_b1        = (const float*)d_in[32];
    const float* c_w2        = (const float*)d_in[33];
    const float* c_b2        = (const float*)d_in[34];
    const float* n_w1        = (const float*)d_in[35];
    const float* n_b1        = (const float*)d_in[36];
    const float* n_w2        = (const float*)d_in[37];
    const float* n_b2        = (const float*)d_in[38];
    const float* r_w1        = (const float*)d_in[39];
    const float* r_b1        = (const float*)d_in[40];
    const float* r_w2        = (const float*)d_in[41];
    const float* r_b2        = (const float*)d_in[42];
    const float* o_w1        = (const float*)d_in[43];
    const float* o_b1        = (const float*)d_in[44];
    const float* o_w2        = (const float*)d_in[45];
    const float* o_b2        = (const float*)d_in[46];
    const int* user_ids      = (const int*)d_in[47];
    const int* movie_ids     = (const int*)d_in[48];
    const int* franchise_ids = (const int*)d_in[49];
    const int* entry_types   = (const int*)d_in[50];
    const int* relation_mat  = (const int*)d_in[51];

    // ---- workspace layout ----
    u16* up16 = (u16*)d_ws;
    u16* proj_wt = up16;                                   // [1024][1536]
    u16* wqkv_t  = proj_wt + (size_t)1024 * 1536;          // [4][3072][1024]
    u16* wo_t    = wqkv_t  + (size_t)4 * 3072 * 1024;      // [4][1024][1024]
    u16* fw1_buf = wo_t    + (size_t)4 * 1024 * 1024;      // [4096][1024] (per-layer)
    u16* fw2_buf = fw1_buf + (size_t)4096 * 1024;          // [1024][4096] (per-layer)
    u16* mq_t    = fw2_buf + (size_t)1024 * 4096;          // [1024][1024]
    u16* mk_t    = mq_t    + (size_t)1024 * 1024;
    u16* mv_t    = mk_t    + (size_t)1024 * 1024;
    u16* mo_t    = mv_t    + (size_t)1024 * 1024;
    u16* c_w1t   = mo_t    + (size_t)1024 * 1024;          // [1024][2048]
    u16* n_w1t   = c_w1t   + (size_t)1024 * 2048;          // [1024][2048]
    u16* r_w1t   = n_w1t   + (size_t)1024 * 2048;          // [1024][3072]
    u16* o_w1t   = r_w1t   + (size_t)1024 * 3072;          // [512][1024]
    u16* ffb     = o_w1t   + (size_t)512 * 1024;           // [6400][4096]  (union with xinb)
    u16* xinb    = ffb;                                    // [6400][1536]  (dead after proj)
    u16* xb      = ffb     + (size_t)BS_ * FF_;            // [6400][1024]
    u16* qkvb    = xb      + (size_t)BS_ * D_;             // [6400][3072]
    u16* ctxb    = qkvb    + (size_t)BS_ * 3 * D_;         // [6400][1024]
    u16* ob      = ctxb    + (size_t)BS_ * D_;             // [6400][1024]
    u16* ueb     = ob      + (size_t)BS_ * D_;             // [128][1024]
    u16* upb_pre = ueb     + (size_t)B_ * D_;              // [128][1024]
    u16* upb     = upb_pre + (size_t)B_ * D_;              // [128][1024]
    u16* seqb    = upb     + (size_t)B_ * D_;              // [128][1024]
    u16* cib     = seqb    + (size_t)B_ * D_;              // [128][2048]
    u16* rib     = cib     + (size_t)B_ * 2 * D_;          // [128][3072]
    float* fp    = (float*)(rib + (size_t)B_ * 3 * D_);
    float* bqkv  = fp;                                     // [4][3072]
    float* pet   = bqkv + 4 * 3072;                        // [50][1024]
    float* h1    = pet  + 50 * 1024;                       // [128][1024]
    float* ho    = h1   + (size_t)B_ * D_;                 // [128][512]

    // ---- d_out layout ----
    float* xout    = (float*)d_out;                 // [BS, D]
    float* comp    = xout + (size_t)BS_ * D_;       // [B,1]
    float* logits  = comp + B_;                     // [B,V]
    float* rating  = logits + (size_t)B_ * V_;      // [B,1]
    float* order   = rating + B_;                   // [B,2]
    float* upref   = order + 2 * B_;                // [B,D]

    dim3 blk(256);

    // ---- weight conversion pass ----
    wtrans<<<dim3(32, 48, 1), blk, 0, stream>>>(proj_w, proj_wt, 1536, 1024, 0, 0, 0);
    wtrans<<<dim3(32, 32, 4), blk, 0, stream>>>(wq, wqkv_t, 1024, 1024, 1048576, 3145728, 0);
    wtrans<<<dim3(32, 32, 4), blk, 0, stream>>>(wk, wqkv_t, 1024, 1024, 1048576, 3145728, 1024);
    wtrans<<<dim3(32, 32, 4), blk, 0, stream>>>(wv, wqkv_t, 1024, 1024, 1048576, 3145728, 2048);
    wtrans<<<dim3(32, 32, 4), blk, 0, stream>>>(wo, wo_t, 1024, 1024, 1048576, 1048576, 0);
    wtrans<<<dim3(32, 32, 1), blk, 0, stream>>>(mq_w, mq_t, 1024, 1024, 0, 0, 0);
    wtrans<<<dim3(32, 32, 1), blk, 0, stream>>>(mk_w, mk_t, 1024, 1024, 0, 0, 0);
    wtrans<<<dim3(32, 32, 1), blk, 0, stream>>>(mv_w, mv_t, 1024, 1024, 0, 0, 0);
    wtrans<<<dim3(32, 32, 1), blk, 0, stream>>>(mo_w, mo_t, 1024, 1024, 0, 0, 0);
    wtrans<<<dim3(32, 64, 1), blk, 0, stream>>>(c_w1, c_w1t, 2048, 1024, 0, 0, 0);
    wtrans<<<dim3(32, 64, 1), blk, 0, stream>>>(n_w1, n_w1t, 2048, 1024, 0, 0, 0);
    wtrans<<<dim3(32, 96, 1), blk, 0, stream>>>(r_w1, r_w1t, 3072, 1024, 0, 0, 0);
    wtrans<<<dim3(16, 32, 1), blk, 0, stream>>>(o_w1, o_w1t, 1024, 512, 0, 0, 0);
    copy_cols<<<4, blk, 0, stream>>>(bq, bqkv, 1024, 3072, 0);
    copy_cols<<<4, blk, 0, stream>>>(bk, bqkv, 1024, 3072, 1024);
    copy_cols<<<4, blk, 0, stream>>>(bv, bqkv, 1024, 3072, 2048);
    pe_table<<<S_, blk, 0, stream>>>(pet);

    // ---- encoder input (PE fused into proj epilogue) ----
    embed_concat<<<BS_, blk, 0, stream>>>(movie_table, fran_table, entry_table,
                                          movie_ids, franchise_ids, entry_types, xinb);
    gemm_bf16<<<dim3(8, 50), blk, 0, stream>>>(xinb, proj_wt, proj_b, xout, xb,
                                               BS_, D_, 3 * E_, 0, pet);

    // ---- transformer layers ----
    for (int l = 0; l < L_; ++l) {
        gemm_bf16<<<dim3(24, 50), blk, 0, stream>>>(xb, wqkv_t + (size_t)l * 3145728,
                                                    bqkv + l * 3072, nullptr, qkvb,
                                                    BS_, 3 * D_, D_, 0, nullptr);
        attn_kernel<<<B_ * H_, blk, 0, stream>>>(qkvb, rel_table + (size_t)l * 5 * DK_,
                                                 relation_mat, ctxb);
        gemm_bf16<<<dim3(8, 50), blk, 0, stream>>>(ctxb, wo_t + (size_t)l * 1048576,
                                                   bo + l * D_, nullptr, ob,
                                                   BS_, D_, D_, 0, nullptr);
        add_ln<<<BS_, blk, 0, stream>>>(ob, xout, aln_g + l * D_, aln_b + l * D_, xout, xb);
        wtrans<<<dim3(128, 32, 1), blk, 0, stream>>>(f_w1 + (size_t)l * D_ * FF_, fw1_buf,
                                                     1024, 4096, 0, 0, 0);
        gemm_bf16<<<dim3(32, 50), blk, 0, stream>>>(xb, fw1_buf, f_b1 + l * FF_,
                                                    nullptr, ffb, BS_, FF_, D_, 1, nullptr);
        wtrans<<<dim3(32, 128, 1), blk, 0, stream>>>(f_w2 + (size_t)l * FF_ * D_, fw2_buf,
                                                     4096, 1024, 0, 0, 0);
        gemm_bf16<<<dim3(8, 50), blk, 0, stream>>>(ffb, fw2_buf, f_b2 + l * D_,
                                                   nullptr, ob, BS_, D_, FF_, 0, nullptr);
        add_ln<<<BS_, blk, 0, stream>>>(ob, xout, ln_g + l * D_, ln_b + l * D_, xout, xb);
    }

    // ---- user cross-attention ----
    gather_user<<<B_, blk, 0, stream>>>(user_table, user_ids, ueb);
    gemm_bf16<<<dim3(8, 1), blk, 0, stream>>>(ueb, mq_t, mq_b, nullptr, qkvb, B_, D_, D_, 0, nullptr);
    gemm_bf16<<<dim3(8, 50), blk, 0, stream>>>(xb, mk_t, mk_b, nullptr, ctxb, BS_, D_, D_, 0, nullptr);
    gemm_bf16<<<dim3(8, 50), blk, 0, stream>>>(xb, mv_t, mv_b, nullptr, ob, BS_, D_, D_, 0, nullptr);
    cross_attn<<<B_ * H_, dim3(64), 0, stream>>>(qkvb, ctxb, ob, upb_pre);
    gemm_bf16<<<dim3(8, 1), blk, 0, stream>>>(upb_pre, mo_t, mo_b, upref, upb, B_, D_, D_, 0, nullptr);

    // ---- sequence mean + concats ----
    seq_mean<<<B_, blk, 0, stream>>>(xout, seqb);
    copy_cols_b<<<B_, blk, 0, stream>>>(upb,  cib, D_, 2 * D_, 0);
    copy_cols_b<<<B_, blk, 0, stream>>>(seqb, cib, D_, 2 * D_, D_);
    copy_cols_b<<<B_, blk, 0, stream>>>(ueb,  rib, D_, 3 * D_, 0);
    copy_cols_b<<<B_, blk, 0, stream>>>(upb,  rib, D_, 3 * D_, D_);
    copy_cols_b<<<B_, blk, 0, stream>>>(seqb, rib, D_, 3 * D_, 2 * D_);

    // ---- heads ----
    gemm_bf16<<<dim3(8, 1), blk, 0, stream>>>(cib, c_w1t, c_b1, h1, nullptr, B_, D_, 2 * D_, 1, nullptr);
    gemm_bias_act<<<dim3(1, 2), blk, 0, stream>>>(h1, c_w2, c_b2, comp, B_, 1, D_, 2);
    gemm_bf16<<<dim3(8, 1), blk, 0, stream>>>(cib, n_w1t, n_b1, h1, nullptr, B_, D_, 2 * D_, 1, nullptr);
    gemm_mfma<<<dim3(782, 1), blk, 0, stream>>>(h1, n_w2, n_b2, logits, B_, V_, D_, 0);
    gemm_bf16<<<dim3(8, 1), blk, 0, stream>>>(rib, r_w1t, r_b1, h1, nullptr, B_, D_, 3 * D_, 1, nullptr);
    gemm_bias_act<<<dim3(1, 2), blk, 0, stream>>>(h1, r_w2, r_b2, rating, B_, 1, D_, 0);
    gemm_bf16<<<dim3(4, 1), blk, 0, stream>>>(upb, o_w1t, o_b1, ho, nullptr, B_, 512, D_, 1, nullptr);
    gemm_bias_act<<<dim3(1, 2), blk, 0, stream>>>(ho, o_w2, o_b2, h1, B_, 2, 512, 0);
    order_softmax<<<1, dim3(128), 0, stream>>>(h1, order);
}

// Round 6
// 2222.416 us; speedup vs baseline: 5.5769x; 1.1932x over previous
//
#include <hip/hip_runtime.h>
#include <hip/hip_bf16.h>
#include <math.h>

// ---------------- problem constants ----------------
#define B_   128
#define S_   50
#define BS_  (B_*S_)        // 6400
#define E_   512
#define D_   1024
#define H_   16
#define DK_  64
#define L_   4
#define FF_  4096
#define V_   100000

typedef short bf8_t __attribute__((ext_vector_type(8)));
typedef float f32x4 __attribute__((ext_vector_type(4)));
typedef unsigned short u16;

__device__ __forceinline__ float gelu_exact(float x) {
    return 0.5f * x * (1.0f + erff(x * 0.70710678118654752440f));
}
// fp32 -> bf16 bits, round-to-nearest-even
__device__ __forceinline__ u16 f2bf(float f) {
    unsigned int u = __float_as_uint(f);
    return (u16)((u + 0x7FFFu + ((u >> 16) & 1u)) >> 16);
}
__device__ __forceinline__ float bf2f(u16 u) {
    return __uint_as_float(((unsigned int)u) << 16);
}

// async global->LDS, 16B per lane (dest is wave-uniform base + lane*16)
__device__ __forceinline__ void gload16(const u16* g, u16* l) {
    auto* g1 = reinterpret_cast<const __attribute__((address_space(1))) unsigned int*>(
                   reinterpret_cast<uintptr_t>(g));
    auto* l3 = reinterpret_cast<__attribute__((address_space(3))) unsigned int*>(
                   reinterpret_cast<uintptr_t>(l));
    __builtin_amdgcn_global_load_lds(g1, l3, 16, 0, 0);
}

// ---------------- weight transpose bodies ----------------
__device__ __forceinline__ void wtrans_body(
    const float* __restrict__ W, u16* __restrict__ Wt,
    int K, int N, int nb, int kb, int dstRowOff)
{
    __shared__ float t[32][33];
    int c = threadIdx.x & 31, r0 = threadIdx.x >> 5;  // r0 in 0..7
    #pragma unroll
    for (int rr = 0; rr < 32; rr += 8)
        t[rr + r0][c] = W[(size_t)(kb + rr + r0) * N + nb + c];
    __syncthreads();
    #pragma unroll
    for (int rr = 0; rr < 32; rr += 8)
        Wt[(size_t)(dstRowOff + nb + rr + r0) * K + kb + c] = f2bf(t[c][rr + r0]);
}

__global__ __launch_bounds__(256) void wtrans(
    const float* __restrict__ W, u16* __restrict__ Wt,
    int K, int N, long srcLS, long dstLS, int dstRowOff)
{
    int l = blockIdx.z;
    wtrans_body(W + (size_t)l * srcLS, Wt + (size_t)l * dstLS,
                K, N, blockIdx.x * 32, blockIdx.y * 32, dstRowOff);
}

// q/k/v for 4 layers in one dispatch: z = which*4 + layer
__global__ __launch_bounds__(256) void wtrans_qkv(
    const float* __restrict__ wq, const float* __restrict__ wk, const float* __restrict__ wv,
    u16* __restrict__ dst)
{
    int z = blockIdx.z;
    int l = z & 3, which = z >> 2;
    const float* W = (which == 0 ? wq : which == 1 ? wk : wv) + (size_t)l * (D_ * D_);
    u16* Wt = dst + (size_t)l * (3 * D_ * D_) + (size_t)which * (D_ * D_);
    wtrans_body(W, Wt, D_, D_, blockIdx.x * 32, blockIdx.y * 32, 0);
}

struct WT4 { const float* s[4]; u16* d[4]; };
__global__ __launch_bounds__(256) void wtrans4(WT4 p)
{
    int z = blockIdx.z;
    wtrans_body(p.s[z], p.d[z], D_, D_, blockIdx.x * 32, blockIdx.y * 32, 0);
}

// both FF weights of one layer in one dispatch
__global__ __launch_bounds__(256) void wtrans_ff(
    const float* __restrict__ w1, const float* __restrict__ w2,
    u16* __restrict__ d1, u16* __restrict__ d2)
{
    if (blockIdx.z == 0)
        wtrans_body(w1, d1, D_, FF_, blockIdx.x * 32, blockIdx.y * 32, 0);   // [1024][4096] -> [4096][1024]
    else
        wtrans_body(w2, d2, FF_, D_, blockIdx.y * 32, blockIdx.x * 32, 0);   // [4096][1024] -> [1024][4096]
}

// ---------------- embedding gather + concat (bf16 out) ----------------
__global__ __launch_bounds__(256) void embed_concat(
    const float* __restrict__ mt, const float* __restrict__ ft, const float* __restrict__ et,
    const int* __restrict__ mids, const int* __restrict__ fids, const int* __restrict__ eids,
    u16* __restrict__ xinb)
{
    int bs = blockIdx.x;
    int mid = mids[bs], fid = fids[bs], eid = eids[bs];
    const float* srcs[3] = { mt + (size_t)mid * E_, ft + (size_t)fid * E_, et + (size_t)eid * E_ };
    u16* dst = xinb + (size_t)bs * (3 * E_);
    for (int i = threadIdx.x; i < 384; i += 256) {
        int seg = i >> 7, off = i & 127;
        float4 v = reinterpret_cast<const float4*>(srcs[seg])[off];
        ushort4 b;
        b.x = f2bf(v.x); b.y = f2bf(v.y); b.z = f2bf(v.z); b.w = f2bf(v.w);
        reinterpret_cast<ushort4*>(dst + seg * E_)[off] = b;
    }
}

// ---------------- positional encoding table [50][1024] ----------------
__global__ __launch_bounds__(256) void pe_table(float* __restrict__ pet)
{
    int s = blockIdx.x;
    const float c = -logf(10000.0f) / 512.0f;
    for (int d = threadIdx.x; d < D_; d += 256) {
        int second = d >= 512;
        int cc = second ? d - 512 : d;
        int i = cc >> 1;
        float div = expf(c * (float)(2 * i));
        float a = (float)s * div * (second ? 1.5f : 1.0f);
        pet[s * D_ + d] = (cc & 1) ? cosf(a) : sinf(a);
    }
}

// ---------------- bf16 MFMA GEMM v3: depth-2 counted-vmcnt pipeline ----------------
// A bf16 [M,lda], Wt bf16 [N,K] row-major, bias fp32[N]. M%128==0, N%128==0, K%32==0, nk>=2.
// LDS: [row][chunk] holds global[row][chunk ^ ((row>>1)&3)], chunk = 8 u16 (16B).
__global__ __launch_bounds__(256) void gemm_bf16(
    const u16* __restrict__ A, int lda, const u16* __restrict__ Wt,
    const float* __restrict__ bias, float* __restrict__ Cf,
    u16* __restrict__ Cb, int ldcb, u16* __restrict__ Cb2, int ldcb2,
    int M, int N, int K, int act, const float* __restrict__ pe)
{
    __shared__ u16 As[2 * 4096];
    __shared__ u16 Bs[2 * 4096];
    const int tid  = threadIdx.x;
    const int lane = tid & 63;
    const int wid  = tid >> 6;
    const int wr   = wid >> 1, wc = wid & 1;

    // XCD-bijective swizzle (m204)
    const int gx  = gridDim.x;
    const int nwg = gx * gridDim.y;
    {
    }
    int orig = blockIdx.y * gx + blockIdx.x;
    int qq = nwg >> 3, rr = nwg & 7, xcd = orig & 7, idx = orig >> 3;
    int wgid = (xcd < rr) ? (xcd * (qq + 1) + idx)
                          : (rr * (qq + 1) + (xcd - rr) * qq + idx);
    const int rowBase = (wgid / gx) * 128;
    const int colBase = (wgid % gx) * 128;

    const int fr = lane & 15;
    const int hi = lane >> 4;

    // staging geometry: wave wid covers tile rows [wid*32, wid*32+32)
    const int sRowL  = lane >> 2;
    const int sChunk = lane & 3;
    const int gRow0  = (wid << 5) + sRowL;
    const int skey   = (gRow0 >> 1) & 3;       // same for gRow0+16
    const int gC     = (sChunk ^ skey) << 3;   // inverse-swizzled global chunk (elems)
    const u16* aS0 = A  + (size_t)(rowBase + gRow0) * lda + gC;
    const u16* aS1 = aS0 + (size_t)16 * lda;
    const u16* bS0 = Wt + (size_t)(colBase + gRow0) * K + gC;
    const u16* bS1 = bS0 + (size_t)16 * K;
    const int ldsW0 = (wid << 5) << 5;
    const int ldsW1 = ldsW0 + (16 << 5);

    // fragment read (swizzled)
    const int swz = ((hi ^ ((fr >> 1) & 3)) << 3);
    const int aRd = (wr * 64 + fr) * 32 + swz;    // + m*512
    const int bRd = (wc * 64 + fr) * 32 + swz;    // + n*512

    f32x4 acc[4][4] = {};
    const int nk = K >> 5;

    // prologue: T0 -> buf0, T1 -> buf1; wait own T0 (vmcnt(4)) then barrier
    gload16(aS0, As + ldsW0);
    gload16(aS1, As + ldsW1);
    gload16(bS0, Bs + ldsW0);
    gload16(bS1, Bs + ldsW1);
    __builtin_amdgcn_sched_barrier(0);
    gload16(aS0 + 32, As + 4096 + ldsW0);
    gload16(aS1 + 32, As + 4096 + ldsW1);
    gload16(bS0 + 32, Bs + 4096 + ldsW0);
    gload16(bS1 + 32, Bs + 4096 + ldsW1);
    __builtin_amdgcn_sched_barrier(0);
    asm volatile("s_waitcnt vmcnt(4)\n\ts_barrier" ::: "memory");
    __builtin_amdgcn_sched_barrier(0);

    for (int t = 0; t < nk; ++t) {
        const int cur = t & 1;
        const u16* bA = As + cur * 4096;
        const u16* bB = Bs + cur * 4096;
        bf8_t af[4], bf[4];
        #pragma unroll
        for (int m = 0; m < 4; ++m)
            af[m] = *reinterpret_cast<const bf8_t*>(&bA[aRd + m * 512]);
        #pragma unroll
        for (int n = 0; n < 4; ++n)
            bf[n] = *reinterpret_cast<const bf8_t*>(&bB[bRd + n * 512]);
        #pragma unroll
        for (int m = 0; m < 4; ++m)
            #pragma unroll
            for (int n = 0; n < 4; ++n)
                acc[m][n] = __builtin_amdgcn_mfma_f32_16x16x32_bf16(af[m], bf[n], acc[m][n], 0, 0, 0);
        if (t == nk - 1) break;
        // barrier #1: all waves' ds_reads of buf[cur] drained -> safe to overwrite
        __builtin_amdgcn_sched_barrier(0);
        asm volatile("s_waitcnt lgkmcnt(0)\n\ts_barrier" ::: "memory");
        __builtin_amdgcn_sched_barrier(0);
        if (t + 2 < nk) {
            const int kb = (t + 2) << 5;
            u16* dA = As + cur * 4096;
            u16* dB = Bs + cur * 4096;
            gload16(aS0 + kb, dA + ldsW0);
            gload16(aS1 + kb, dA + ldsW1);
            gload16(bS0 + kb, dB + ldsW0);
            gload16(bS1 + kb, dB + ldsW1);
            __builtin_amdgcn_sched_barrier(0);
            // outstanding: T(t+1)=4 + T(t+2)=4 -> wait 4 => T(t+1) resident
            asm volatile("s_waitcnt vmcnt(4)\n\ts_barrier" ::: "memory");
        } else {
            asm volatile("s_waitcnt vmcnt(0)\n\ts_barrier" ::: "memory");
        }
        __builtin_amdgcn_sched_barrier(0);
    }

    // epilogue: C/D map col=lane&15, row=(lane>>4)*4+reg
    const int orow = (lane >> 4) << 2;
    #pragma unroll
    for (int m = 0; m < 4; ++m) {
        int r0 = rowBase + wr * 64 + m * 16 + orow;
        #pragma unroll
        for (int n = 0; n < 4; ++n) {
            int c = colBase + wc * 64 + n * 16 + fr;
            float bv = bias ? bias[c] : 0.0f;
            #pragma unroll
            for (int r = 0; r < 4; ++r) {
                float v = acc[m][n][r] + bv;
                if (act == 1) v = gelu_exact(v);
                if (pe) v += pe[(size_t)((r0 + r) % S_) * N + c];
                if (Cf)  Cf [(size_t)(r0 + r) * N + c] = v;
                if (Cb)  Cb [(size_t)(r0 + r) * ldcb  + c] = f2bf(v);
                if (Cb2) Cb2[(size_t)(r0 + r) * ldcb2 + c] = f2bf(v);
            }
        }
    }
}

// ---------------- logits GEMM: fp32 W streamed, reg-staged pipeline ----------------
// M = 128 fixed (grid.y == 1). A fp32 [128, lda], W fp32 [K, N], C fp32 [128, N].
__global__ __launch_bounds__(256) void gemm_logits(
    const float* __restrict__ A, int lda, const float* __restrict__ W,
    const float* __restrict__ bias, float* __restrict__ C, int N, int K)
{
    __shared__ u16 As[2][128][40];
    __shared__ u16 Bs[2][128][40];
    const int tid  = threadIdx.x;
    const int lane = tid & 63;
    const int wid  = tid >> 6;
    const int wr   = wid >> 1, wc = wid & 1;
    const int colBase = blockIdx.x * 128;

    const int a_r = tid >> 1;
    const int a_h = (tid & 1) << 4;
    const int b_c = tid & 127;
    const int b_h = (tid >> 7) << 4;

    const int fr = lane & 15;
    const int fk = (lane >> 4) << 3;

    f32x4 acc[4][4] = {};
    const int nvalid = N - colBase;
    const bool valid = b_c < nvalid;
    const int nk = K >> 5;

    float4 aR[4];
    float  bR[16];

    auto LD = [&](int kb) {
        const float* Ap = A + (size_t)a_r * lda + kb + a_h;
        #pragma unroll
        for (int q = 0; q < 4; ++q)
            aR[q] = *reinterpret_cast<const float4*>(Ap + q * 4);
        const float* Wp = W + (size_t)(kb + b_h) * N + colBase + b_c;
        #pragma unroll
        for (int kk = 0; kk < 16; ++kk)
            bR[kk] = valid ? Wp[(size_t)kk * N] : 0.0f;
    };
    auto ST = [&](int buf) {
        #pragma unroll
        for (int q = 0; q < 4; ++q) {
            ushort4 bb;
            bb.x = f2bf(aR[q].x); bb.y = f2bf(aR[q].y);
            bb.z = f2bf(aR[q].z); bb.w = f2bf(aR[q].w);
            *reinterpret_cast<ushort4*>(&As[buf][a_r][a_h + q * 4]) = bb;
        }
        u16 tmp[16];
        #pragma unroll
        for (int kk = 0; kk < 16; ++kk) tmp[kk] = f2bf(bR[kk]);
        *reinterpret_cast<bf8_t*>(&Bs[buf][b_c][b_h])     = *reinterpret_cast<const bf8_t*>(tmp);
        *reinterpret_cast<bf8_t*>(&Bs[buf][b_c][b_h + 8]) = *reinterpret_cast<const bf8_t*>(tmp + 8);
    };

    LD(0); ST(0);
    __syncthreads();

    for (int t = 0; t < nk; ++t) {
        if (t + 1 < nk) LD((t + 1) << 5);   // issue-early: overlaps compute below
        const int cur = t & 1;
        bf8_t af[4], bfv[4];
        #pragma unroll
        for (int m = 0; m < 4; ++m)
            af[m] = *reinterpret_cast<const bf8_t*>(&As[cur][wr * 64 + m * 16 + fr][fk]);
        #pragma unroll
        for (int n = 0; n < 4; ++n)
            bfv[n] = *reinterpret_cast<const bf8_t*>(&Bs[cur][wc * 64 + n * 16 + fr][fk]);
        #pragma unroll
        for (int m = 0; m < 4; ++m)
            #pragma unroll
            for (int n = 0; n < 4; ++n)
                acc[m][n] = __builtin_amdgcn_mfma_f32_16x16x32_bf16(af[m], bfv[n], acc[m][n], 0, 0, 0);
        if (t + 1 < nk) ST(cur ^ 1);        // write-late after compute
        __syncthreads();
    }

    const int orow = (lane >> 4) << 2;
    #pragma unroll
    for (int m = 0; m < 4; ++m) {
        int r0 = wr * 64 + m * 16 + orow;
        #pragma unroll
        for (int n = 0; n < 4; ++n) {
            int c = colBase + wc * 64 + n * 16 + fr;
            if (c < N) {
                float bv = bias ? bias[c] : 0.0f;
                #pragma unroll
                for (int r = 0; r < 4; ++r)
                    C[(size_t)(r0 + r) * N + c] = acc[m][n][r] + bv;
            }
        }
    }
}

// ---------------- self-attention (per (b,h) block), bf16 qkv merged [BS,3072] ----------------
__global__ __launch_bounds__(256) void attn_kernel(
    const u16* __restrict__ qkv, const float* __restrict__ rt, const int* __restrict__ rm,
    u16* __restrict__ ctxb)
{
    int bh = blockIdx.x;
    int b = bh >> 4, h = bh & 15;
    __shared__ float qs[S_][DK_ + 1], ks[S_][DK_ + 1], vs[S_][DK_ + 1];
    __shared__ float rts[5][DK_];
    __shared__ float Rs[S_][8];
    int tid = threadIdx.x;
    int wave = tid >> 6, lane = tid & 63;

    for (int idx = tid; idx < S_ * DK_; idx += 256) {
        int s = idx >> 6, d = idx & 63;
        size_t g = ((size_t)(b * S_ + s)) * (3 * D_) + h * DK_ + d;
        qs[s][d] = bf2f(qkv[g]);
        ks[s][d] = bf2f(qkv[g + D_]);
        vs[s][d] = bf2f(qkv[g + 2 * D_]);
    }
    for (int i = tid; i < 5 * DK_; i += 256)
        rts[i >> 6][i & 63] = rt[i];
    __syncthreads();

    for (int t = tid; t < S_ * 5; t += 256) {
        int i = t / 5, r = t - 5 * i;
        float a = 0.0f;
        #pragma unroll 8
        for (int d = 0; d < DK_; ++d) a += qs[i][d] * rts[r][d];
        Rs[i][r] = a;
    }
    __syncthreads();

    const float scale = 0.125f;
    for (int i = wave; i < S_; i += 4) {
        float sc = -INFINITY;
        if (lane < S_) {
            float acc = 0.0f;
            #pragma unroll 8
            for (int d = 0; d < DK_; ++d) acc += qs[i][d] * ks[lane][d];
            sc = acc * scale + 0.5f * Rs[i][rm[i * S_ + lane]];
        }
        float m = sc;
        #pragma unroll
        for (int off = 32; off; off >>= 1) m = fmaxf(m, __shfl_xor(m, off));
        float e = (lane < S_) ? expf(sc - m) : 0.0f;
        float sum = e;
        #pragma unroll
        for (int off = 32; off; off >>= 1) sum += __shfl_xor(sum, off);
        float aval = e / sum;

        float acc = 0.0f;
        for (int j = 0; j < S_; ++j) {
            float aj = __shfl(aval, j);
            acc += aj * vs[j][lane];
        }
        ctxb[((size_t)(b * S_ + i)) * D_ + h * DK_ + lane] = f2bf(acc);
    }
}

// ---------------- add + layernorm: out = LN(bf16(a) + res); writes fp32 + bf16 ----------------
__global__ __launch_bounds__(256) void add_ln(
    const u16* __restrict__ a, const float* __restrict__ res,
    const float* __restrict__ g, const float* __restrict__ be,
    float* __restrict__ outf, u16* __restrict__ outb)
{
    int row = blockIdx.x, tid = threadIdx.x;
    const u16* pa = a + (size_t)row * D_;
    const float* pr = res + (size_t)row * D_;
    float vals[4];
    float s = 0.0f;
    #pragma unroll
    for (int t = 0; t < 4; ++t) {
        float v = bf2f(pa[tid + t * 256]) + pr[tid + t * 256];
        vals[t] = v;
        s += v;
    }
    __shared__ float red[8];
    #pragma unroll
    for (int off = 32; off; off >>= 1) s += __shfl_xor(s, off);
    int wave = tid >> 6, lane = tid & 63;
    if (lane == 0) red[wave] = s;
    __syncthreads();
    float mean = (red[0] + red[1] + red[2] + red[3]) * (1.0f / D_);
    float vv = 0.0f;
    #pragma unroll
    for (int t = 0; t < 4; ++t) {
        float d = vals[t] - mean;
        vv += d * d;
    }
    #pragma unroll
    for (int off = 32; off; off >>= 1) vv += __shfl_xor(vv, off);
    if (lane == 0) red[4 + wave] = vv;
    __syncthreads();
    float var = (red[4] + red[5] + red[6] + red[7]) * (1.0f / D_);
    float rstd = rsqrtf(var + 1e-5f);
    #pragma unroll
    for (int t = 0; t < 4; ++t) {
        int c = tid + t * 256;
        float v = (vals[t] - mean) * rstd * g[c] + be[c];
        outf[(size_t)row * D_ + c] = v;
        outb[(size_t)row * D_ + c] = f2bf(v);
    }
}

// ---------------- user embedding gather (bf16, two destinations) ----------------
__global__ __launch_bounds__(256) void gather_user(
    const float* __restrict__ ut, const int* __restrict__ ids,
    u16* __restrict__ o1, int ld1, u16* __restrict__ o2, int ld2)
{
    int b = blockIdx.x;
    int uid = ids[b];
    for (int d = threadIdx.x; d < D_; d += 256) {
        u16 v = f2bf(ut[(size_t)uid * D_ + d]);
        o1[(size_t)b * ld1 + d] = v;
        o2[(size_t)b * ld2 + d] = v;
    }
}

// ---------------- cross attention (q_len = 1); K/V merged [BS][2048] ----------------
__global__ __launch_bounds__(64) void cross_attn(
    const u16* __restrict__ qh, const u16* __restrict__ kv, u16* __restrict__ up)
{
    int bh = blockIdx.x;
    int b = bh >> 4, h = bh & 15;
    int lane = threadIdx.x;
    __shared__ float qv[DK_];
    qv[lane] = bf2f(qh[(size_t)b * D_ + h * DK_ + lane]);
    __syncthreads();
    float sc = -INFINITY;
    if (lane < S_) {
        float acc = 0.0f;
        const u16* krow = kv + ((size_t)(b * S_ + lane)) * 2048 + h * DK_;
        #pragma unroll 8
        for (int d = 0; d < DK_; ++d) acc += qv[d] * bf2f(krow[d]);
        sc = acc * 0.125f;
    }
    float m = sc;
    #pragma unroll
    for (int off = 32; off; off >>= 1) m = fmaxf(m, __shfl_xor(m, off));
    float e = (lane < S_) ? expf(sc - m) : 0.0f;
    float sum = e;
    #pragma unroll
    for (int off = 32; off; off >>= 1) sum += __shfl_xor(sum, off);
    float aval = e / sum;
    float acc = 0.0f;
    for (int j = 0; j < S_; ++j) {
        float aj = __shfl(aval, j);
        acc += aj * bf2f(kv[((size_t)(b * S_ + j)) * 2048 + 1024 + h * DK_ + lane]);
    }
    up[(size_t)b * D_ + h * DK_ + lane] = f2bf(acc);
}

// ---------------- sequence mean (bf16, two destinations) ----------------
__global__ __launch_bounds__(256) void seq_mean(
    const float* __restrict__ x,
    u16* __restrict__ o1, int ld1, u16* __restrict__ o2, int ld2)
{
    int b = blockIdx.x;
    for (int d = threadIdx.x; d < D_; d += 256) {
        float s = 0.0f;
        for (int si = 0; si < S_; ++si)
            s += x[((size_t)(b * S_ + si)) * D_ + d];
        u16 v = f2bf(s * (1.0f / S_));
        o1[(size_t)b * ld1 + d] = v;
        o2[(size_t)b * ld2 + d] = v;
    }
}

// ---------------- column copy (fp32, bias concats) ----------------
__global__ __launch_bounds__(256) void copy_cols(
    const float* __restrict__ src, float* __restrict__ dst,
    int width, int dstStride, int dstOff)
{
    int r = blockIdx.x;
    for (int c = threadIdx.x; c < width; c += 256)
        dst[(size_t)r * dstStride + dstOff + c] = src[(size_t)r * width + c];
}

// ---------------- fused final heads: completion / rating / order ----------------
__global__ __launch_bounds__(256) void heads_final(
    const float* __restrict__ h1cn, const float* __restrict__ h1r, const float* __restrict__ ho,
    const float* __restrict__ c_w2, const float* __restrict__ c_b2,
    const float* __restrict__ r_w2, const float* __restrict__ r_b2,
    const float* __restrict__ o_w2, const float* __restrict__ o_b2,
    float* __restrict__ comp, float* __restrict__ rating, float* __restrict__ order)
{
    int b = blockIdx.x;
    int lane = threadIdx.x & 63, wv = threadIdx.x >> 6;
    if (wv == 0) {
        float s = 0.0f;
        for (int d = lane; d < D_; d += 64) s += h1cn[(size_t)b * 2048 + d] * c_w2[d];
        #pragma unroll
        for (int off = 32; off; off >>= 1) s += __shfl_xor(s, off);
        if (lane == 0) comp[b] = 1.0f / (1.0f + expf(-(s + c_b2[0])));
    } else if (wv == 1) {
        float s = 0.0f;
        for (int d = lane; d < D_; d += 64) s += h1r[(size_t)b * D_ + d] * r_w2[d];
        #pragma unroll
        for (int off = 32; off; off >>= 1) s += __shfl_xor(s, off);
        if (lane == 0) rating[b] = s + r_b2[0];
    } else if (wv == 2) {
        float s0 = 0.0f, s1 = 0.0f;
        for (int d = lane; d < 512; d += 64) {
            float hv = ho[(size_t)b * 512 + d];
            s0 += hv * o_w2[d * 2];
            s1 += hv * o_w2[d * 2 + 1];
        }
        #pragma unroll
        for (int off = 32; off; off >>= 1) { s0 += __shfl_xor(s0, off); s1 += __shfl_xor(s1, off); }
        if (lane == 0) {
            float a = s0 + o_b2[0], c = s1 + o_b2[1];
            float m = fmaxf(a, c);
            float ea = expf(a - m), ec = expf(c - m);
            float s = ea + ec;
            order[b * 2] = ea / s;
            order[b * 2 + 1] = ec / s;
        }
    }
}

// ---------------- host-side launcher ----------------
extern "C" void kernel_launch(void* const* d_in, const int* in_sizes, int n_in,
                              void* d_out, int out_size, void* d_ws, size_t ws_size,
                              hipStream_t stream) {
    const float* movie_table = (const float*)d_in[0];
    const float* fran_table  = (const float*)d_in[1];
    const float* entry_table = (const float*)d_in[2];
    const float* proj_w      = (const float*)d_in[3];
    const float* proj_b      = (const float*)d_in[4];
    const float* wq          = (const float*)d_in[5];
    const float* bq          = (const float*)d_in[6];
    const float* wk          = (const float*)d_in[7];
    const float* bk          = (const float*)d_in[8];
    const float* wv          = (const float*)d_in[9];
    const float* bv          = (const float*)d_in[10];
    const float* wo          = (const float*)d_in[11];
    const float* bo          = (const float*)d_in[12];
    const float* rel_table   = (const float*)d_in[13];
    const float* aln_g       = (const float*)d_in[14];
    const float* aln_b       = (const float*)d_in[15];
    const float* f_w1        = (const float*)d_in[16];
    const float* f_b1        = (const float*)d_in[17];
    const float* f_w2        = (const float*)d_in[18];
    const float* f_b2        = (const float*)d_in[19];
    const float* ln_g        = (const float*)d_in[20];
    const float* ln_b        = (const float*)d_in[21];
    const float* user_table  = (const float*)d_in[22];
    const float* mq_w        = (const float*)d_in[23];
    const float* mq_b        = (const float*)d_in[24];
    const float* mk_w        = (const float*)d_in[25];
    const float* mk_b        = (const float*)d_in[26];
    const float* mv_w        = (const float*)d_in[27];
    const float* mv_b        = (const float*)d_in[28];
    const float* mo_w        = (const float*)d_in[29];
    const float* mo_b        = (const float*)d_in[30];
    const float* c_w1        = (const float*)d_in[31];
    const float* c_b1        = (const float*)d_in[32];
    const float* c_w2        = (const float*)d_in[33];
    const float* c_b2        = (const float*)d_in[34];
    const float* n_w1        = (const float*)d_in[35];
    const float* n_b1        = (const float*)d_in[36];
    const float* n_w2        = (const float*)d_in[37];
    const float* n_b2        = (const float*)d_in[38];
    const float* r_w1        = (const float*)d_in[39];
    const float* r_b1        = (const float*)d_in[40];
    const float* r_w2        = (const float*)d_in[41];
    const float* r_b2        = (const float*)d_in[42];
    const float* o_w1        = (const float*)d_in[43];
    const float* o_b1        = (const float*)d_in[44];
    const float* o_w2        = (const float*)d_in[45];
    const float* o_b2        = (const float*)d_in[46];
    const int* user_ids      = (const int*)d_in[47];
    const int* movie_ids     = (const int*)d_in[48];
    const int* franchise_ids = (const int*)d_in[49];
    const int* entry_types   = (const int*)d_in[50];
    const int* relation_mat  = (const int*)d_in[51];

    // ---- workspace layout (u16 units) ----
    u16* up16 = (u16*)d_ws;
    u16* proj_wt = up16;                                   // [1024][1536]
    u16* wqkv_t  = proj_wt + (size_t)1024 * 1536;          // [4][3072][1024]
    u16* wo_t    = wqkv_t  + (size_t)4 * 3072 * 1024;      // [4][1024][1024]
    u16* fw1_buf = wo_t    + (size_t)4 * 1024 * 1024;      // [4096][1024] (per-layer)
    u16* fw2_buf = fw1_buf + (size_t)4096 * 1024;          // [1024][4096] (per-layer)
    u16* mq_t    = fw2_buf + (size_t)1024 * 4096;          // [1024][1024]
    u16* mk_t    = mq_t    + (size_t)1024 * 1024;
    u16* mv_t    = mk_t    + (size_t)1024 * 1024;
    u16* mo_t    = mv_t    + (size_t)1024 * 1024;
    u16* cn_w1t  = mo_t    + (size_t)1024 * 1024;          // [2048][2048] (c rows 0-1023, n rows 1024-2047)
    u16* r_w1t   = cn_w1t  + (size_t)2048 * 2048;          // [1024][3072]
    u16* o_w1t   = r_w1t   + (size_t)1024 * 3072;          // [512][1024]
    u16* ffb     = o_w1t   + (size_t)512 * 1024;           // [6400][4096] (union with xinb)
    u16* xinb    = ffb;                                    // [6400][1536]
    u16* xb      = ffb     + (size_t)BS_ * FF_;            // [6400][1024]
    u16* qkvb    = xb      + (size_t)BS_ * D_;             // [6400][3072]
    u16* kvb     = qkvb    + (size_t)BS_ * 3 * D_;         // [6400][2048] (ctx + mk|mv)
    u16* ctxb    = kvb;                                    //   layer ctx uses first [6400][1024]
    u16* ob      = kvb     + (size_t)BS_ * D_;             //   [6400][1024]
    u16* ueb     = kvb     + (size_t)BS_ * 2 * D_;         // [128][1024]
    u16* upb_pre = ueb     + (size_t)B_ * D_;              // [128][1024]
    u16* cib     = upb_pre + (size_t)B_ * D_;              // [128][2048]
    u16* rib     = cib     + (size_t)B_ * 2 * D_;          // [128][3072]
    float* fp    = (float*)(rib + (size_t)B_ * 3 * D_);
    float* bqkv  = fp;                                     // [4][3072]
    float* bcn   = bqkv + 4 * 3072;                        // [2048]
    float* bkv   = bcn  + 2048;                            // [2048]
    float* pet   = bkv  + 2048;                            // [50][1024]
    float* h1cn  = pet  + 50 * 1024;                       // [128][2048]
    float* h1r   = h1cn + (size_t)B_ * 2048;               // [128][1024]
    float* ho    = h1r  + (size_t)B_ * D_;                 // [128][512]

    // ---- d_out layout ----
    float* xout    = (float*)d_out;                 // [BS, D]
    float* comp    = xout + (size_t)BS_ * D_;       // [B,1]
    float* logits  = comp + B_;                     // [B,V]
    float* rating  = logits + (size_t)B_ * V_;      // [B,1]
    float* order   = rating + B_;                   // [B,2]
    float* upref   = order + 2 * B_;                // [B,D]

    dim3 blk(256);

    // ---- weight conversion pass ----
    wtrans<<<dim3(32, 48, 1), blk, 0, stream>>>(proj_w, proj_wt, 1536, 1024, 0, 0, 0);
    wtrans_qkv<<<dim3(32, 32, 12), blk, 0, stream>>>(wq, wk, wv, wqkv_t);
    wtrans<<<dim3(32, 32, 4), blk, 0, stream>>>(wo, wo_t, 1024, 1024, 1048576, 1048576, 0);
    WT4 wm;
    wm.s[0] = mq_w; wm.s[1] = mk_w; wm.s[2] = mv_w; wm.s[3] = mo_w;
    wm.d[0] = mq_t; wm.d[1] = mk_t; wm.d[2] = mv_t; wm.d[3] = mo_t;
    wtrans4<<<dim3(32, 32, 4), blk, 0, stream>>>(wm);
    wtrans<<<dim3(32, 64, 1), blk, 0, stream>>>(c_w1, cn_w1t, 2048, 1024, 0, 0, 0);
    wtrans<<<dim3(32, 64, 1), blk, 0, stream>>>(n_w1, cn_w1t, 2048, 1024, 0, 0, 1024);
    wtrans<<<dim3(32, 96, 1), blk, 0, stream>>>(r_w1, r_w1t, 3072, 1024, 0, 0, 0);
    wtrans<<<dim3(16, 32, 1), blk, 0, stream>>>(o_w1, o_w1t, 1024, 512, 0, 0, 0);
    copy_cols<<<4, blk, 0, stream>>>(bq, bqkv, 1024, 3072, 0);
    copy_cols<<<4, blk, 0, stream>>>(bk, bqkv, 1024, 3072, 1024);
    copy_cols<<<4, blk, 0, stream>>>(bv, bqkv, 1024, 3072, 2048);
    copy_cols<<<1, blk, 0, stream>>>(c_b1, bcn, 1024, 2048, 0);
    copy_cols<<<1, blk, 0, stream>>>(n_b1, bcn, 1024, 2048, 1024);
    copy_cols<<<1, blk, 0, stream>>>(mk_b, bkv, 1024, 2048, 0);
    copy_cols<<<1, blk, 0, stream>>>(mv_b, bkv, 1024, 2048, 1024);
    pe_table<<<S_, blk, 0, stream>>>(pet);

    // ---- encoder input (PE fused into proj epilogue) ----
    embed_concat<<<BS_, blk, 0, stream>>>(movie_table, fran_table, entry_table,
                                          movie_ids, franchise_ids, entry_types, xinb);
    gemm_bf16<<<dim3(8, 50), blk, 0, stream>>>(xinb, 1536, proj_wt, proj_b,
                                               xout, xb, 1024, nullptr, 0,
                                               BS_, D_, 1536, 0, pet);

    // ---- transformer layers ----
    for (int l = 0; l < L_; ++l) {
        gemm_bf16<<<dim3(24, 50), blk, 0, stream>>>(xb, 1024, wqkv_t + (size_t)l * 3145728,
                                                    bqkv + l * 3072, nullptr, qkvb, 3072,
                                                    nullptr, 0, BS_, 3 * D_, D_, 0, nullptr);
        attn_kernel<<<B_ * H_, blk, 0, stream>>>(qkvb, rel_table + (size_t)l * 5 * DK_,
                                                 relation_mat, ctxb);
        gemm_bf16<<<dim3(8, 50), blk, 0, stream>>>(ctxb, 1024, wo_t + (size_t)l * 1048576,
                                                   bo + l * D_, nullptr, ob, 1024,
                                                   nullptr, 0, BS_, D_, D_, 0, nullptr);
        add_ln<<<BS_, blk, 0, stream>>>(ob, xout, aln_g + l * D_, aln_b + l * D_, xout, xb);
        wtrans_ff<<<dim3(128, 32, 2), blk, 0, stream>>>(f_w1 + (size_t)l * D_ * FF_,
                                                        f_w2 + (size_t)l * FF_ * D_,
                                                        fw1_buf, fw2_buf);
        gemm_bf16<<<dim3(32, 50), blk, 0, stream>>>(xb, 1024, fw1_buf, f_b1 + l * FF_,
                                                    nullptr, ffb, 4096, nullptr, 0,
                                                    BS_, FF_, D_, 1, nullptr);
        gemm_bf16<<<dim3(8, 50), blk, 0, stream>>>(ffb, 4096, fw2_buf, f_b2 + l * D_,
                                                   nullptr, ob, 1024, nullptr, 0,
                                                   BS_, D_, FF_, 0, nullptr);
        add_ln<<<BS_, blk, 0, stream>>>(ob, xout, ln_g + l * D_, ln_b + l * D_, xout, xb);
    }

    // ---- user cross-attention ----
    gather_user<<<B_, blk, 0, stream>>>(user_table, user_ids, ueb, 1024, rib, 3072);
    gemm_bf16<<<dim3(8, 1), blk, 0, stream>>>(ueb, 1024, mq_t, mq_b, nullptr, qkvb, 1024,
                                              nullptr, 0, B_, D_, D_, 0, nullptr);
    gemm_bf16<<<dim3(16, 50), blk, 0, stream>>>(xb, 1024, mk_t, bkv, nullptr, kvb, 2048,
                                                nullptr, 0, BS_, 2 * D_, D_, 0, nullptr);
    cross_attn<<<B_ * H_, dim3(64), 0, stream>>>(qkvb, kvb, upb_pre);
    gemm_bf16<<<dim3(8, 1), blk, 0, stream>>>(upb_pre, 1024, mo_t, mo_b, upref,
                                              cib, 2048, rib + 1024, 3072,
                                              B_, D_, D_, 0, nullptr);

    // ---- sequence mean (writes into both concats) ----
    seq_mean<<<B_, blk, 0, stream>>>(xout, cib + 1024, 2048, rib + 2048, 3072);

    // ---- heads ----
    gemm_bf16<<<dim3(16, 1), blk, 0, stream>>>(cib, 2048, cn_w1t, bcn, h1cn,
                                               nullptr, 0, nullptr, 0,
                                               B_, 2048, 2048, 1, nullptr);
    gemm_bf16<<<dim3(8, 1), blk, 0, stream>>>(rib, 3072, r_w1t, r_b1, h1r,
                                              nullptr, 0, nullptr, 0,
                                              B_, D_, 3072, 1, nullptr);
    gemm_bf16<<<dim3(4, 1), blk, 0, stream>>>(cib, 2048, o_w1t, o_b1, ho,
                                              nullptr, 0, nullptr, 0,
                                              B_, 512, D_, 1, nullptr);
    gemm_logits<<<dim3(782, 1), blk, 0, stream>>>(h1cn + 1024, 2048, n_w2, n_b2,
                                                  logits, V_, D_);
    heads_final<<<B_, blk, 0, stream>>>(h1cn, h1r, ho, c_w2, c_b2, r_w2, r_b2,
                                        o_w2, o_b2, comp, rating, order);
}